// Round 8
// baseline (417.107 us; speedup 1.0000x reference)
//
#include <hip/hip_runtime.h>
#include <cstddef>

// Problem constants (match reference)
constexpr int Bc = 32;    // batch
constexpr int Sc = 512;   // source length
constexpr int Hc = 256;   // hidden
constexpr int Fc = 256;   // filter
constexpr int Tc = 2048;  // max mel length
constexpr int Kc = 3;     // conv kernel
constexpr float EPSc = 1e-5f;

// MFMA types
typedef __attribute__((ext_vector_type(8))) short bf16x8;
typedef __attribute__((ext_vector_type(4))) float f32x4;
typedef unsigned long long ull;
struct alignas(16) U16 { ull a, b; };

// Tiling: fused L1+L2, MB=64 L2 output rows per 256-thread block.
// launch_bounds(256,3): 170-reg budget, 3 blocks/CU, LDS 3x39.9KB.
// Grid 2304 = 3 exact rounds of 768 co-resident blocks.
// L1 rows p=0..63 (t=s0-1+p) PLUS halo rows 64,65 folded into the SAME
// K1 loop as a 5th row-tile (B fragments reused; no extra B stream).
// Input staged ARB=68 rows (t = s0-2 .. s0+65).
constexpr int ALD = 264;     // LDS row stride (shorts): 4-dword row bank-shift -> 2-way max (free)
constexpr int MB  = 64;      // L2 output rows per block (divides T and S)
constexpr int ARB = 68;      // staged input rows

// Weight tensor: [co][k*256+ci] bf16, row stride 768
constexpr int KW = 768;
constexpr int KW16 = 16 * KW;               // 12288
constexpr size_t WTSZ = (size_t)Fc * KW;    // shorts per prepped tensor

// ---- output layout (flat f32) ----
constexpr size_t O_OUT   = 0;                                   // (B,T,H)
constexpr size_t O_PP    = O_OUT  + (size_t)Bc*Tc*Hc;           // (B,T)
constexpr size_t O_EP    = O_PP   + (size_t)Bc*Tc;              // (B,T)
constexpr size_t O_LOGD  = O_EP   + (size_t)Bc*Tc;              // (B,S)
constexpr size_t O_DUR   = O_LOGD + (size_t)Bc*Sc;              // (B,S)
constexpr size_t O_MLEN  = O_DUR  + (size_t)Bc*Sc;              // (B,)
constexpr size_t O_MMASK = O_MLEN + (size_t)Bc;                 // (B,T)

// ---- workspace layout (bytes) ----
constexpr size_t W_CUM  = 0;                 // int[B*S]
constexpr size_t W_MEL  = 0x10000;           // int[B]
constexpr size_t W_CORR = 0x60000;           // float[2][6][256] (A1[3],B1[3] per pred)
constexpr size_t W_WT   = 0x70000;           // short[6][256][768] = 2.25MB
constexpr size_t W_XBF  = 0x2C0000;          // bf16 x: short[B][S][H] = 8MB

// prep kernel block ranges
constexpr int PREP_CR0  = 1152;   // [0,1152) wprep; [1152,1158) corr
constexpr int PREP_XB0  = 1158;   // [1158,3206) xbf: 2048 blocks
constexpr int PREP_SC0  = 3206;   // [3206,3238) scan: 32 batches
constexpr int PREP_NB   = 3238;

// per-predictor argument bundle (passed by value)
struct PArgs {
  const float *sc;                       // scalar conditioning (pitch/energy), null for dur
  const float *cb1, *lng1, *lnb1;        // layer-1 bias / LN
  const float *cb2, *lng2, *lnb2;        // layer-2 bias / LN
  const float *lw, *lb;                  // projection
  float *pred;                           // output (B,N)
};

__device__ __forceinline__ short f2bf(float f) {
  union { float f; unsigned u; } a; a.f = f;
  unsigned r = a.u + 0x7FFFu + ((a.u >> 16) & 1u);   // RNE
  return (short)(r >> 16);
}

__device__ __forceinline__ ull pack4bf(float4 v) {
  return (ull)(unsigned short)f2bf(v.x) |
         ((ull)(unsigned short)f2bf(v.y) << 16) |
         ((ull)(unsigned short)f2bf(v.z) << 32) |
         ((ull)(unsigned short)f2bf(v.w) << 48);
}

// searchsorted(cum[0..Sc), t, 'right'), clamped to Sc-1
__device__ __forceinline__ int ssearch(const int* __restrict__ c, int t) {
  int lo = 0, hi = Sc;
  while (lo < hi) {
    int mid = (lo + hi) >> 1;
    if (c[mid] <= t) lo = mid + 1; else hi = mid;
  }
  return lo > (Sc - 1) ? (Sc - 1) : lo;
}

// ============================================================
// prep: wprep + corr + xbf + scan merged in one launch (block ranges).
// ============================================================
__global__ __launch_bounds__(256) void prep_kernel(
    const float* __restrict__ pit_cw, const float* __restrict__ ene_cw,
    const float* __restrict__ dur_cw,
    const float* __restrict__ pc1_w, const float* __restrict__ pc1_b,
    const float* __restrict__ ec1_w, const float* __restrict__ ec1_b,
    const float* __restrict__ x, const int* __restrict__ src_dur,
    short* __restrict__ wt, float* __restrict__ corr, short* __restrict__ xb,
    int* __restrict__ cum, int* __restrict__ mel_i,
    float* __restrict__ dur_out, float* __restrict__ mlen_out) {
  __shared__ float tile[32][33];
  const int gid = blockIdx.x;
  const int tid = threadIdx.x;

  if (gid < PREP_CR0) {
    // ---- wprep: w[k][ci][co] f32 -> w_t[co][k*256+ci] bf16 ----
    int z = gid / 192, rem = gid % 192;           // z = pred*2 + layer
    int bx = rem % 24, by = rem / 24;
    const float* base = (z >> 1) == 0 ? pit_cw : (z >> 1) == 1 ? ene_cw : dur_cw;
    const float* w = base + (size_t)(z & 1) * Kc * Fc * Fc;   // [768][256]
    short* out = wt + (size_t)z * WTSZ;                        // [256][768]
    int kci0 = bx * 32, co0 = by * 32;
    int j = tid & 31, i0 = tid >> 5;
    #pragma unroll
    for (int p = 0; p < 4; p++) {
      int i = i0 + p * 8;
      tile[i][j] = w[(size_t)(kci0 + i) * Fc + co0 + j];
    }
    __syncthreads();
    #pragma unroll
    for (int p = 0; p < 4; p++) {
      int i = i0 + p * 8;
      out[(size_t)(co0 + i) * KW + kci0 + j] = f2bf(tile[j][i]);
    }
  } else if (gid < PREP_XB0) {
    // ---- corr: A1[k][co] = sum_ci w[k][ci][co]*scw[ci]; B1 with scb ----
    int id = gid - PREP_CR0;
    int p = id / 3, k = id % 3;
    int co = tid;
    const float* w   = p == 0 ? pit_cw : ene_cw;
    const float* scw = p == 0 ? pc1_w : ec1_w;
    const float* scb = p == 0 ? pc1_b : ec1_b;
    float a = 0.f, bsum = 0.f;
    for (int ci = 0; ci < 256; ci++) {
      float wv = w[(size_t)((k << 8) + ci) * 256 + co];
      a += wv * scw[ci];
      bsum += wv * scb[ci];
    }
    float* o = corr + (size_t)p * 6 * 256;
    o[k * 256 + co] = a;
    o[(3 + k) * 256 + co] = bsum;
  } else if (gid < PREP_SC0) {
    // ---- xbf: x -> bf16, 8 floats/thread ----
    size_t g = (size_t)(gid - PREP_XB0) * 256 + tid;
    float4 v0 = *(const float4*)(x + g * 8);
    float4 v1 = *(const float4*)(x + g * 8 + 4);
    U16 o; o.a = pack4bf(v0); o.b = pack4bf(v1);
    *(U16*)(xb + g * 8) = o;
  } else {
    // ---- scan: per-batch inclusive duration scan (first 64 threads) ----
    if (tid < 64) {
      int b = gid - PREP_SC0;
      int lane = tid;
      const int per = Sc / 64;                // 8
      int base = b * Sc + lane * per;
      int v[per];
      int s = 0;
      #pragma unroll
      for (int i = 0; i < per; i++) { v[i] = src_dur[base + i]; s += v[i]; }
      int pre = s;
      #pragma unroll
      for (int d = 1; d < 64; d <<= 1) {
        int o = __shfl_up(pre, d, 64);
        if (lane >= d) pre += o;
      }
      int run = pre - s;
      #pragma unroll
      for (int i = 0; i < per; i++) {
        run += v[i];
        cum[base + i] = run;
        dur_out[base + i] = (float)v[i];
      }
      if (lane == 63) { mel_i[b] = run; mlen_out[b] = (float)run; }
    }
  }
}

// ============================================================
// Main K-loop: 768-deep (3 conv taps x 256 ci), 3-stage B prefetch.
// HALO=true additionally accumulates one 16-row halo tile (rows 64..79,
// clamped reads; only 64/65 kept) reusing the SAME B fragments.
// ============================================================
template <bool HALO>
__device__ __forceinline__ void run_kloop(const short* __restrict__ wp,
                                          const short* __restrict__ a_lds,
                                          int l15, int quad,
                                          f32x4 (&acc)[4][4], f32x4 (&accx)[4]) {
  bf16x8 vbuf[3][4];
  #pragma unroll
  for (int nt = 0; nt < 4; nt++) {
    vbuf[0][nt] = *(const bf16x8*)(wp + nt * KW16);
    vbuf[1][nt] = *(const bf16x8*)(wp + nt * KW16 + 32);
  }
  #pragma unroll 1
  for (int kb = 0; kb < 24; kb += 3) {
    #pragma unroll
    for (int sub = 0; sub < 3; sub++) {
      int kbi = kb + sub;
      int kld = kbi + 2; if (kld > 23) kld = 23;
      #pragma unroll
      for (int nt = 0; nt < 4; nt++)
        vbuf[(sub + 2) % 3][nt] = *(const bf16x8*)(wp + nt * KW16 + kld * 32);
      const int kk = kbi >> 3, ci0 = (kbi & 7) * 32;
      bf16x8 av[4];
      #pragma unroll
      for (int mt = 0; mt < 4; mt++)
        av[mt] = *(const bf16x8*)&a_lds[(mt * 16 + l15 + kk) * ALD + ci0 + quad * 8];
      bf16x8 ax;
      if (HALO) {
        int rx = 64 + l15 + kk; if (rx > ARB - 1) rx = ARB - 1;  // clamp, discarded
        ax = *(const bf16x8*)&a_lds[rx * ALD + ci0 + quad * 8];
      }
      #pragma unroll
      for (int mt = 0; mt < 4; mt++)
        #pragma unroll
        for (int nt = 0; nt < 4; nt++)
          acc[mt][nt] = __builtin_amdgcn_mfma_f32_16x16x32_bf16(av[mt], vbuf[sub % 3][nt], acc[mt][nt], 0, 0, 0);
      if (HALO) {
        #pragma unroll
        for (int nt = 0; nt < 4; nt++)
          accx[nt] = __builtin_amdgcn_mfma_f32_16x16x32_bf16(ax, vbuf[sub % 3][nt], accx[nt], 0, 0, 0);
      }
    }
  }
}

// ============================================================
// Merged fused variance-predictor: all 3 predictors in one launch.
// blocks [0,1024) pitch, [1024,2048) energy, [2048,2304) duration.
// 256 thr (4 waves), MB=64 rows/block, (256,3): 170-reg budget, 3 blk/CU.
// Inline searchsorted (no idx tensor); OOB-zero folded into writeback.
// ============================================================
__global__ __launch_bounds__(256, 3) void fused_all_kernel(
    const short* __restrict__ xbf, const int* __restrict__ cum,
    const int* __restrict__ mel_i, const unsigned char* __restrict__ src_mask,
    const short* __restrict__ wt_base, const float* __restrict__ corr_base,
    PArgs pa, PArgs ea, PArgs da) {
  __shared__ short a_lds[ARB * ALD];         // 35.9KB; input tile then L1 output
  __shared__ int   s_idx[ARB];
  __shared__ float s_sc[ARB];
  __shared__ float part_s[MB][4];            // reused for projection partials
  __shared__ float part_s2[MB][4];
  __shared__ float part_sx[16][4];
  __shared__ float part_s2x[16][4];
  __shared__ float smean[MB], srstd[MB];
  __shared__ float smeanx[16], srstdx[16];

  const int tid = threadIdx.x;
  const int gid = blockIdx.x;

  int pred, loc;
  if (gid < 1024)      { pred = 0; loc = gid; }
  else if (gid < 2048) { pred = 1; loc = gid - 1024; }
  else                 { pred = 2; loc = gid - 2048; }
  const bool gather = pred < 2;
  const int tile = gather ? (loc & 31) : (loc & 7);
  const int b    = gather ? (loc >> 5) : (loc >> 3);
  const int N    = gather ? Tc : Sc;
  const int s0   = tile * MB;

  PArgs ar = pred == 0 ? pa : (pred == 1 ? ea : da);
  const short* wt1 = wt_base + (size_t)(pred * 2) * WTSZ;
  const short* wt2 = wt1 + WTSZ;
  const float* corr = corr_base + (size_t)pred * 6 * 256;   // valid for pred<2

  const int lane = tid & 63, wv = tid >> 6;       // wv 0..3
  const int l15 = lane & 15, quad = lane >> 4;
  const int co0 = wv * 64;                        // wave's co quarter

  // ---- phase A: inline searchsorted + sc preload (gather path) ----
  if (gather) {
    if (tid < ARB) {
      int t = s0 - 2 + tid;
      bool v = (t >= 0 && t < N && t < mel_i[b]);
      int i = v ? ssearch(cum + b * Sc, t) : -1;
      s_idx[tid] = i;
      s_sc[tid] = v ? ar.sc[b * Sc + i] : 0.0f;
    }
    __syncthreads();
  }

  // ---- phase B: bf16 row staging (pure copies, 8 rows/iter) ----
  {
    int r0 = tid >> 5, c0 = (tid & 31) * 8;
    #pragma unroll
    for (int it = 0; it < 9; it++) {
      int r = it * 8 + r0;
      if (r < ARB) {
        U16 v;
        if (gather) {
          int i = s_idx[r];
          int is = i < 0 ? 0 : i;
          v = *(const U16*)(xbf + ((size_t)b * Sc + is) * Hc + c0);
          if (i < 0) { v.a = 0; v.b = 0; }
        } else {
          int t = s0 - 2 + r;
          int ts = t < 0 ? 0 : (t > N - 1 ? N - 1 : t);
          v = *(const U16*)(xbf + ((size_t)b * N + ts) * Hc + c0);
          if (t < 0 || t >= N) { v.a = 0; v.b = 0; }
        }
        *(U16*)&a_lds[r * ALD + c0] = v;
      }
    }
  }
  __syncthreads();

  // ---- K-loop 1: conv layer-1, 64 main rows + folded halo tile ----
  f32x4 acc[4][4];
  f32x4 accx[4];
  #pragma unroll
  for (int i = 0; i < 4; i++) {
    accx[i] = (f32x4){0.f, 0.f, 0.f, 0.f};
    #pragma unroll
    for (int j = 0; j < 4; j++) acc[i][j] = (f32x4){0.f, 0.f, 0.f, 0.f};
  }
  const short* wp1 = wt1 + (size_t)(co0 + l15) * KW + quad * 8;
  run_kloop<true>(wp1, a_lds, l15, quad, acc, accx);

  // ---- epilogue-1: bias (+rank-6 sc correction) + ReLU + LN stats ----
  float cbv[4], gv[4], bv2[4];
  #pragma unroll
  for (int nt = 0; nt < 4; nt++) {
    int ch = co0 + nt * 16 + l15;
    cbv[nt] = ar.cb1[ch]; gv[nt] = ar.lng1[ch]; bv2[nt] = ar.lnb1[ch];
  }
  float a1v[3][4], b1v[3][4];
  if (gather) {
    #pragma unroll
    for (int k = 0; k < 3; k++)
      #pragma unroll
      for (int nt = 0; nt < 4; nt++) {
        int ch = co0 + nt * 16 + l15;
        a1v[k][nt] = corr[k * 256 + ch];
        b1v[k][nt] = corr[(3 + k) * 256 + ch];
      }
  }
  #pragma unroll
  for (int mt = 0; mt < 4; mt++)
    #pragma unroll
    for (int r = 0; r < 4; r++) {
      int p = mt * 16 + quad * 4 + r;          // L1 row, inputs p..p+2
      float c0s = 0.f, c1s = 0.f, c2s = 0.f, w0 = 0.f, w1 = 0.f, w2 = 0.f;
      if (gather) {
        c0s = s_sc[p]; c1s = s_sc[p + 1]; c2s = s_sc[p + 2];
        w0 = s_idx[p]     >= 0 ? 1.f : 0.f;
        w1 = s_idx[p + 1] >= 0 ? 1.f : 0.f;
        w2 = s_idx[p + 2] >= 0 ? 1.f : 0.f;
      }
      float s = 0.f, s2 = 0.f;
      #pragma unroll
      for (int nt = 0; nt < 4; nt++) {
        float v = acc[mt][nt][r] + cbv[nt];
        if (gather)
          v += c0s * a1v[0][nt] + c1s * a1v[1][nt] + c2s * a1v[2][nt]
             + w0 * b1v[0][nt] + w1 * b1v[1][nt] + w2 * b1v[2][nt];
        v = fmaxf(v, 0.f);
        acc[mt][nt][r] = v;
        s += v; s2 += v * v;
      }
      #pragma unroll
      for (int d = 1; d <= 8; d <<= 1) {
        s += __shfl_xor(s, d, 64);
        s2 += __shfl_xor(s2, d, 64);
      }
      if (l15 == 0) {
        part_s[p][wv] = s; part_s2[p][wv] = s2;
      }
    }

  // ---- halo epilogue: bias (+corr) + ReLU + row stats (rows 64..79) ----
  #pragma unroll
  for (int r = 0; r < 4; r++) {
    int p = 64 + quad * 4 + r;            // L1 row index (garbage for p>=66)
    int i0 = p, i1 = p + 1, i2 = p + 2;
    if (i0 > ARB - 1) i0 = ARB - 1;
    if (i1 > ARB - 1) i1 = ARB - 1;
    if (i2 > ARB - 1) i2 = ARB - 1;
    float c0s = 0.f, c1s = 0.f, c2s = 0.f, w0 = 0.f, w1 = 0.f, w2 = 0.f;
    if (gather) {
      c0s = s_sc[i0]; c1s = s_sc[i1]; c2s = s_sc[i2];
      w0 = s_idx[i0] >= 0 ? 1.f : 0.f;
      w1 = s_idx[i1] >= 0 ? 1.f : 0.f;
      w2 = s_idx[i2] >= 0 ? 1.f : 0.f;
    }
    float s = 0.f, s2 = 0.f;
    #pragma unroll
    for (int nt = 0; nt < 4; nt++) {
      float v = accx[nt][r] + cbv[nt];
      if (gather)
        v += c0s * a1v[0][nt] + c1s * a1v[1][nt] + c2s * a1v[2][nt]
           + w0 * b1v[0][nt] + w1 * b1v[1][nt] + w2 * b1v[2][nt];
      v = fmaxf(v, 0.f);
      accx[nt][r] = v;
      s += v; s2 += v * v;
    }
    #pragma unroll
    for (int d = 1; d <= 8; d <<= 1) {
      s += __shfl_xor(s, d, 64);
      s2 += __shfl_xor(s2, d, 64);
    }
    if (l15 == 0) {
      part_sx[quad * 4 + r][wv] = s; part_s2x[quad * 4 + r][wv] = s2;
    }
  }
  __syncthreads();
  if (tid < MB) {
    float s  = part_s[tid][0] + part_s[tid][1] + part_s[tid][2] + part_s[tid][3];
    float s2 = part_s2[tid][0] + part_s2[tid][1] + part_s2[tid][2] + part_s2[tid][3];
    float m = s * (1.f / Fc);
    float var = s2 * (1.f / Fc) - m * m;
    smean[tid] = m; srstd[tid] = rsqrtf(var + EPSc);
  } else if (tid < MB + 16) {
    int i = tid - MB;
    float s  = part_sx[i][0] + part_sx[i][1] + part_sx[i][2] + part_sx[i][3];
    float s2 = part_s2x[i][0] + part_s2x[i][1] + part_s2x[i][2] + part_s2x[i][3];
    float m = s * (1.f / Fc);
    float var = s2 * (1.f / Fc) - m * m;
    smeanx[i] = m; srstdx[i] = rsqrtf(var + EPSc);
  }
  __syncthreads();

  // ---- LN apply + writeback with OOB-zero folded in (SAME padding) ----
  // main rows 0..63, halo rows 64,65; t outside [0,N) -> write 0.
  #pragma unroll
  for (int mt = 0; mt < 4; mt++)
    #pragma unroll
    for (int r = 0; r < 4; r++) {
      int p = mt * 16 + quad * 4 + r;
      int t = s0 - 1 + p;
      bool oob = (t < 0 || t >= N);
      float m = smean[p], rs = srstd[p];
      #pragma unroll
      for (int nt = 0; nt < 4; nt++) {
        float v = oob ? 0.f : (acc[mt][nt][r] - m) * rs * gv[nt] + bv2[nt];
        a_lds[p * ALD + co0 + nt * 16 + l15] = f2bf(v);
      }
    }
  #pragma unroll
  for (int r = 0; r < 4; r++) {
    int p = 64 + quad * 4 + r;
    if (p < 66) {
      int t = s0 - 1 + p;
      bool oob = (t < 0 || t >= N);
      float m = smeanx[p - 64], rs = srstdx[p - 64];
      #pragma unroll
      for (int nt = 0; nt < 4; nt++) {
        float v = oob ? 0.f : (accx[nt][r] - m) * rs * gv[nt] + bv2[nt];
        a_lds[p * ALD + co0 + nt * 16 + l15] = f2bf(v);
      }
    }
  }
  __syncthreads();

  // ---- K-loop 2: conv layer-2 (reads L1 rows 0..65 from LDS) ----
  #pragma unroll
  for (int i = 0; i < 4; i++)
    #pragma unroll
    for (int j = 0; j < 4; j++) acc[i][j] = (f32x4){0.f, 0.f, 0.f, 0.f};
  const short* wp2 = wt2 + (size_t)(co0 + l15) * KW + quad * 8;
  run_kloop<false>(wp2, a_lds, l15, quad, acc, accx);

  // ---- epilogue-2: bias + ReLU + LN stats ----
  float lwv[4];
  #pragma unroll
  for (int nt = 0; nt < 4; nt++) {
    int ch = co0 + nt * 16 + l15;
    cbv[nt] = ar.cb2[ch]; gv[nt] = ar.lng2[ch]; bv2[nt] = ar.lnb2[ch]; lwv[nt] = ar.lw[ch];
  }
  #pragma unroll
  for (int mt = 0; mt < 4; mt++)
    #pragma unroll
    for (int r = 0; r < 4; r++) {
      float s = 0.f, s2 = 0.f;
      #pragma unroll
      for (int nt = 0; nt < 4; nt++) {
        float v = fmaxf(acc[mt][nt][r] + cbv[nt], 0.f);
        acc[mt][nt][r] = v;
        s += v; s2 += v * v;
      }
      #pragma unroll
      for (int d = 1; d <= 8; d <<= 1) {
        s += __shfl_xor(s, d, 64);
        s2 += __shfl_xor(s2, d, 64);
      }
      if (l15 == 0) {
        int p = mt * 16 + quad * 4 + r;
        part_s[p][wv] = s; part_s2[p][wv] = s2;
      }
    }
  __syncthreads();
  if (tid < MB) {
    float s  = part_s[tid][0] + part_s[tid][1] + part_s[tid][2] + part_s[tid][3];
    float s2 = part_s2[tid][0] + part_s2[tid][1] + part_s2[tid][2] + part_s2[tid][3];
    float m = s * (1.f / Fc);
    float var = s2 * (1.f / Fc) - m * m;
    smean[tid] = m; srstd[tid] = rsqrtf(var + EPSc);
  }
  __syncthreads();

  // ---- LN apply + projection reduce (part_s reused as partials) ----
  #pragma unroll
  for (int mt = 0; mt < 4; mt++)
    #pragma unroll
    for (int r = 0; r < 4; r++) {
      int p = mt * 16 + quad * 4 + r;
      float m = smean[p], rs = srstd[p];
      float s = 0.f;
      #pragma unroll
      for (int nt = 0; nt < 4; nt++) {
        float v = (acc[mt][nt][r] - m) * rs * gv[nt] + bv2[nt];
        s += v * lwv[nt];
      }
      #pragma unroll
      for (int d = 1; d <= 8; d <<= 1) s += __shfl_xor(s, d, 64);
      if (l15 == 0) part_s[p][wv] = s;
    }
  __syncthreads();
  if (tid < MB) {
    int t = s0 + tid;
    if (t < N) {
      float o = part_s[tid][0] + part_s[tid][1] + part_s[tid][2] + part_s[tid][3] + ar.lb[0];
      bool masked;
      if (gather) masked = !(t < mel_i[b]);
      else        masked = (src_mask[(size_t)b * N + t] != 0);
      ar.pred[(size_t)b * N + t] = masked ? 0.f : o;
    }
  }
}

// ============================================================
// out = xe + pp*pc2_w + pc2_b + ep*ec2_w + ec2_b  (float4, 4 rows/block)
// Inline searchsorted (L2-hot cum row); also writes mel_mask.
// ============================================================
__global__ __launch_bounds__(256) void final_kernel(
    const float* __restrict__ x, const int* __restrict__ cum,
    const int* __restrict__ mel_i,
    const float* __restrict__ pp, const float* __restrict__ ep,
    const float* __restrict__ pc2_w, const float* __restrict__ pc2_b,
    const float* __restrict__ ec2_w, const float* __restrict__ ec2_b,
    float* __restrict__ out, float* __restrict__ mmask) {
  int bt = blockIdx.x * 4 + (threadIdx.x >> 6);
  int lane = threadIdx.x & 63;
  int b = bt >> 11, t = bt & (Tc - 1);
  int c4 = lane * 4;
  int i = ssearch(cum + b * Sc, t);     // lanes follow identical path (cached)
  bool val = t < mel_i[b];
  if (lane == 0) mmask[bt] = val ? 0.0f : 1.0f;
  float4 xv = *(const float4*)(x + ((size_t)b * Sc + i) * Hc + c4);
  float p = pp[bt], e = ep[bt];
  float4 pw = *(const float4*)(pc2_w + c4);
  float4 pb = *(const float4*)(pc2_b + c4);
  float4 ew = *(const float4*)(ec2_w + c4);
  float4 eb = *(const float4*)(ec2_b + c4);
  float4 o;
  o.x = (val ? xv.x : 0.f) + p * pw.x + pb.x + e * ew.x + eb.x;
  o.y = (val ? xv.y : 0.f) + p * pw.y + pb.y + e * ew.y + eb.y;
  o.z = (val ? xv.z : 0.f) + p * pw.z + pb.z + e * ew.z + eb.z;
  o.w = (val ? xv.w : 0.f) + p * pw.w + pb.w + e * ew.w + eb.w;
  *(float4*)(out + (size_t)bt * Hc + c4) = o;
}

// ============================================================
extern "C" void kernel_launch(void* const* d_in, const int* in_sizes, int n_in,
                              void* d_out, int out_size, void* d_ws, size_t ws_size,
                              hipStream_t stream) {
  const float* x          = (const float*)d_in[0];
  const unsigned char* sm = (const unsigned char*)d_in[1];
  const float* src_pitch  = (const float*)d_in[3];
  const float* src_energy = (const float*)d_in[4];
  const int*   src_dur    = (const int*)d_in[5];

  const float* dur_cw = (const float*)d_in[7];
  const float* dur_cb = (const float*)d_in[8];
  const float* dur_lng= (const float*)d_in[9];
  const float* dur_lnb= (const float*)d_in[10];
  const float* dur_lw = (const float*)d_in[11];
  const float* dur_lb = (const float*)d_in[12];

  const float* pit_cw = (const float*)d_in[13];
  const float* pit_cb = (const float*)d_in[14];
  const float* pit_lng= (const float*)d_in[15];
  const float* pit_lnb= (const float*)d_in[16];
  const float* pit_lw = (const float*)d_in[17];
  const float* pit_lb = (const float*)d_in[18];

  const float* ene_cw = (const float*)d_in[19];
  const float* ene_cb = (const float*)d_in[20];
  const float* ene_lng= (const float*)d_in[21];
  const float* ene_lnb= (const float*)d_in[22];
  const float* ene_lw = (const float*)d_in[23];
  const float* ene_lb = (const float*)d_in[24];

  const float* pc1_w = (const float*)d_in[25];
  const float* pc1_b = (const float*)d_in[26];
  const float* pc2_w = (const float*)d_in[27];
  const float* pc2_b = (const float*)d_in[28];
  const float* ec1_w = (const float*)d_in[29];
  const float* ec1_b = (const float*)d_in[30];
  const float* ec2_w = (const float*)d_in[31];
  const float* ec2_b = (const float*)d_in[32];

  float* out = (float*)d_out;
  float* o_out   = out + O_OUT;
  float* o_pp    = out + O_PP;
  float* o_ep    = out + O_EP;
  float* o_logd  = out + O_LOGD;
  float* o_dur   = out + O_DUR;
  float* o_mlen  = out + O_MLEN;
  float* o_mmask = out + O_MMASK;

  char* ws = (char*)d_ws;
  int*   w_cum  = (int*)(ws + W_CUM);
  int*   w_mel  = (int*)(ws + W_MEL);
  float* w_corr = (float*)(ws + W_CORR);
  short* w_wt   = (short*)(ws + W_WT);
  short* w_xbf  = (short*)(ws + W_XBF);

  // 1) merged prep: wprep + corr + xbf + scan
  prep_kernel<<<PREP_NB, 256, 0, stream>>>(
      pit_cw, ene_cw, dur_cw, pc1_w, pc1_b, ec1_w, ec1_b,
      x, src_dur, w_wt, w_corr, w_xbf, w_cum, w_mel, o_dur, o_mlen);

  // 2) all three predictors, one launch (2304 = 3 exact rounds of 768):
  //    blocks [0,1024) pitch, [1024,2048) energy, [2048,2304) duration
  PArgs pa = { src_pitch,
               pit_cb, pit_lng, pit_lnb,
               pit_cb + Fc, pit_lng + Fc, pit_lnb + Fc,
               pit_lw, pit_lb, o_pp };
  PArgs ea = { src_energy,
               ene_cb, ene_lng, ene_lnb,
               ene_cb + Fc, ene_lng + Fc, ene_lnb + Fc,
               ene_lw, ene_lb, o_ep };
  PArgs da = { nullptr,
               dur_cb, dur_lng, dur_lnb,
               dur_cb + Fc, dur_lng + Fc, dur_lnb + Fc,
               dur_lw, dur_lb, o_logd };
  fused_all_kernel<<<dim3(2304), 256, 0, stream>>>(
      w_xbf, w_cum, w_mel, sm, w_wt, w_corr, pa, ea, da);

  // 3) final output (+ mel_mask)
  final_kernel<<<(Bc * Tc) / 4, 256, 0, stream>>>(
      x, w_cum, w_mel, o_pp, o_ep, pc2_w, pc2_b, ec2_w, ec2_b, o_out, o_mmask);
}

// Round 9
// 409.445 us; speedup vs baseline: 1.0187x; 1.0187x over previous
//
#include <hip/hip_runtime.h>
#include <cstddef>

// Problem constants (match reference)
constexpr int Bc = 32;    // batch
constexpr int Sc = 512;   // source length
constexpr int Hc = 256;   // hidden
constexpr int Fc = 256;   // filter
constexpr int Tc = 2048;  // max mel length
constexpr int Kc = 3;     // conv kernel
constexpr float EPSc = 1e-5f;

// MFMA types
typedef __attribute__((ext_vector_type(8))) short bf16x8;
typedef __attribute__((ext_vector_type(4))) float f32x4;
typedef unsigned long long ull;
struct alignas(16) U16 { ull a, b; };

// Tiling: fused L1+L2, MB=64 L2 output rows per 256-thread block.
// launch_bounds(256,3): 170-reg budget, 3 blocks/CU, LDS 3x39.9KB.
// Grid 2304 = 3 exact rounds of 768 co-resident blocks.
// L1 rows p=0..63 (t=s0-1+p) PLUS halo rows 64,65 folded into the SAME
// K1 loop as a 5th row-tile (B fragments reused; no extra B stream).
// Input staged ARB=68 rows (t = s0-2 .. s0+65).
constexpr int ALD = 264;     // LDS row stride (shorts): 4-dword row bank-shift -> 2-way max (free)
constexpr int MB  = 64;      // L2 output rows per block (divides T and S)
constexpr int ARB = 68;      // staged input rows

// Weight tensor: [co][k*256+ci] bf16, row stride 768
constexpr int KW = 768;
constexpr int KW16 = 16 * KW;               // 12288
constexpr size_t WTSZ = (size_t)Fc * KW;    // shorts per prepped tensor

// ---- output layout (flat f32) ----
constexpr size_t O_OUT   = 0;                                   // (B,T,H)
constexpr size_t O_PP    = O_OUT  + (size_t)Bc*Tc*Hc;           // (B,T)
constexpr size_t O_EP    = O_PP   + (size_t)Bc*Tc;              // (B,T)
constexpr size_t O_LOGD  = O_EP   + (size_t)Bc*Tc;              // (B,S)
constexpr size_t O_DUR   = O_LOGD + (size_t)Bc*Sc;              // (B,S)
constexpr size_t O_MLEN  = O_DUR  + (size_t)Bc*Sc;              // (B,)
constexpr size_t O_MMASK = O_MLEN + (size_t)Bc;                 // (B,T)

// ---- workspace layout (bytes) ----
constexpr size_t W_CUM  = 0;                 // int[B*S]
constexpr size_t W_MEL  = 0x10000;           // int[B]
constexpr size_t W_IDX  = 0x10100;           // int[B*T] (by-product of pitch blocks)
constexpr size_t W_CORR = 0x60000;           // float[2][6][256] (A1[3],B1[3] per pred)
constexpr size_t W_WT   = 0x70000;           // short[6][256][768] = 2.25MB
constexpr size_t W_XBF  = 0x2C0000;          // bf16 x: short[B][S][H] = 8MB

// prep kernel block ranges
constexpr int PREP_CR0  = 1152;   // [0,1152) wprep; [1152,1158) corr
constexpr int PREP_XB0  = 1158;   // [1158,3206) xbf: 2048 blocks
constexpr int PREP_SC0  = 3206;   // [3206,3238) scan: 32 batches
constexpr int PREP_NB   = 3238;

// per-predictor argument bundle (passed by value)
struct PArgs {
  const float *sc;                       // scalar conditioning (pitch/energy), null for dur
  const float *cb1, *lng1, *lnb1;        // layer-1 bias / LN
  const float *cb2, *lng2, *lnb2;        // layer-2 bias / LN
  const float *lw, *lb;                  // projection
  float *pred;                           // output (B,N)
};

__device__ __forceinline__ short f2bf(float f) {
  union { float f; unsigned u; } a; a.f = f;
  unsigned r = a.u + 0x7FFFu + ((a.u >> 16) & 1u);   // RNE
  return (short)(r >> 16);
}

__device__ __forceinline__ ull pack4bf(float4 v) {
  return (ull)(unsigned short)f2bf(v.x) |
         ((ull)(unsigned short)f2bf(v.y) << 16) |
         ((ull)(unsigned short)f2bf(v.z) << 32) |
         ((ull)(unsigned short)f2bf(v.w) << 48);
}

// searchsorted(cum[0..Sc), t, 'right'), clamped to Sc-1
__device__ __forceinline__ int ssearch(const int* __restrict__ c, int t) {
  int lo = 0, hi = Sc;
  while (lo < hi) {
    int mid = (lo + hi) >> 1;
    if (c[mid] <= t) lo = mid + 1; else hi = mid;
  }
  return lo > (Sc - 1) ? (Sc - 1) : lo;
}

// ============================================================
// prep: wprep + corr + xbf + scan merged in one launch (block ranges).
// ============================================================
__global__ __launch_bounds__(256) void prep_kernel(
    const float* __restrict__ pit_cw, const float* __restrict__ ene_cw,
    const float* __restrict__ dur_cw,
    const float* __restrict__ pc1_w, const float* __restrict__ pc1_b,
    const float* __restrict__ ec1_w, const float* __restrict__ ec1_b,
    const float* __restrict__ x, const int* __restrict__ src_dur,
    short* __restrict__ wt, float* __restrict__ corr, short* __restrict__ xb,
    int* __restrict__ cum, int* __restrict__ mel_i,
    float* __restrict__ dur_out, float* __restrict__ mlen_out) {
  __shared__ float tile[32][33];
  const int gid = blockIdx.x;
  const int tid = threadIdx.x;

  if (gid < PREP_CR0) {
    // ---- wprep: w[k][ci][co] f32 -> w_t[co][k*256+ci] bf16 ----
    int z = gid / 192, rem = gid % 192;           // z = pred*2 + layer
    int bx = rem % 24, by = rem / 24;
    const float* base = (z >> 1) == 0 ? pit_cw : (z >> 1) == 1 ? ene_cw : dur_cw;
    const float* w = base + (size_t)(z & 1) * Kc * Fc * Fc;   // [768][256]
    short* out = wt + (size_t)z * WTSZ;                        // [256][768]
    int kci0 = bx * 32, co0 = by * 32;
    int j = tid & 31, i0 = tid >> 5;
    #pragma unroll
    for (int p = 0; p < 4; p++) {
      int i = i0 + p * 8;
      tile[i][j] = w[(size_t)(kci0 + i) * Fc + co0 + j];
    }
    __syncthreads();
    #pragma unroll
    for (int p = 0; p < 4; p++) {
      int i = i0 + p * 8;
      out[(size_t)(co0 + i) * KW + kci0 + j] = f2bf(tile[j][i]);
    }
  } else if (gid < PREP_XB0) {
    // ---- corr: A1[k][co] = sum_ci w[k][ci][co]*scw[ci]; B1 with scb ----
    int id = gid - PREP_CR0;
    int p = id / 3, k = id % 3;
    int co = tid;
    const float* w   = p == 0 ? pit_cw : ene_cw;
    const float* scw = p == 0 ? pc1_w : ec1_w;
    const float* scb = p == 0 ? pc1_b : ec1_b;
    float a = 0.f, bsum = 0.f;
    for (int ci = 0; ci < 256; ci++) {
      float wv = w[(size_t)((k << 8) + ci) * 256 + co];
      a += wv * scw[ci];
      bsum += wv * scb[ci];
    }
    float* o = corr + (size_t)p * 6 * 256;
    o[k * 256 + co] = a;
    o[(3 + k) * 256 + co] = bsum;
  } else if (gid < PREP_SC0) {
    // ---- xbf: x -> bf16, 8 floats/thread ----
    size_t g = (size_t)(gid - PREP_XB0) * 256 + tid;
    float4 v0 = *(const float4*)(x + g * 8);
    float4 v1 = *(const float4*)(x + g * 8 + 4);
    U16 o; o.a = pack4bf(v0); o.b = pack4bf(v1);
    *(U16*)(xb + g * 8) = o;
  } else {
    // ---- scan: per-batch inclusive duration scan (first 64 threads) ----
    if (tid < 64) {
      int b = gid - PREP_SC0;
      int lane = tid;
      const int per = Sc / 64;                // 8
      int base = b * Sc + lane * per;
      int v[per];
      int s = 0;
      #pragma unroll
      for (int i = 0; i < per; i++) { v[i] = src_dur[base + i]; s += v[i]; }
      int pre = s;
      #pragma unroll
      for (int d = 1; d < 64; d <<= 1) {
        int o = __shfl_up(pre, d, 64);
        if (lane >= d) pre += o;
      }
      int run = pre - s;
      #pragma unroll
      for (int i = 0; i < per; i++) {
        run += v[i];
        cum[base + i] = run;
        dur_out[base + i] = (float)v[i];
      }
      if (lane == 63) { mel_i[b] = run; mlen_out[b] = (float)run; }
    }
  }
}

// ============================================================
// Main K-loop: 768-deep (3 conv taps x 256 ci), 3-stage B prefetch.
// HALO=true additionally accumulates one 16-row halo tile (rows 64..79,
// clamped reads; only 64/65 kept) reusing the SAME B fragments.
// MFMA cluster wrapped in s_setprio(1/0) — 3 independent blocks/SIMD
// at different phases gives the scheduler role diversity (T5 regime).
// ============================================================
template <bool HALO>
__device__ __forceinline__ void run_kloop(const short* __restrict__ wp,
                                          const short* __restrict__ a_lds,
                                          int l15, int quad,
                                          f32x4 (&acc)[4][4], f32x4 (&accx)[4]) {
  bf16x8 vbuf[3][4];
  #pragma unroll
  for (int nt = 0; nt < 4; nt++) {
    vbuf[0][nt] = *(const bf16x8*)(wp + nt * KW16);
    vbuf[1][nt] = *(const bf16x8*)(wp + nt * KW16 + 32);
  }
  #pragma unroll 1
  for (int kb = 0; kb < 24; kb += 3) {
    #pragma unroll
    for (int sub = 0; sub < 3; sub++) {
      int kbi = kb + sub;
      int kld = kbi + 2; if (kld > 23) kld = 23;
      #pragma unroll
      for (int nt = 0; nt < 4; nt++)
        vbuf[(sub + 2) % 3][nt] = *(const bf16x8*)(wp + nt * KW16 + kld * 32);
      const int kk = kbi >> 3, ci0 = (kbi & 7) * 32;
      bf16x8 av[4];
      #pragma unroll
      for (int mt = 0; mt < 4; mt++)
        av[mt] = *(const bf16x8*)&a_lds[(mt * 16 + l15 + kk) * ALD + ci0 + quad * 8];
      bf16x8 ax;
      if (HALO) {
        int rx = 64 + l15 + kk; if (rx > ARB - 1) rx = ARB - 1;  // clamp, discarded
        ax = *(const bf16x8*)&a_lds[rx * ALD + ci0 + quad * 8];
      }
      __builtin_amdgcn_s_setprio(1);
      #pragma unroll
      for (int mt = 0; mt < 4; mt++)
        #pragma unroll
        for (int nt = 0; nt < 4; nt++)
          acc[mt][nt] = __builtin_amdgcn_mfma_f32_16x16x32_bf16(av[mt], vbuf[sub % 3][nt], acc[mt][nt], 0, 0, 0);
      if (HALO) {
        #pragma unroll
        for (int nt = 0; nt < 4; nt++)
          accx[nt] = __builtin_amdgcn_mfma_f32_16x16x32_bf16(ax, vbuf[sub % 3][nt], accx[nt], 0, 0, 0);
      }
      __builtin_amdgcn_s_setprio(0);
    }
  }
}

// ============================================================
// Merged fused variance-predictor: all 3 predictors in one launch.
// blocks [0,1024) pitch, [1024,2048) energy, [2048,2304) duration.
// 256 thr (4 waves), MB=64 rows/block, (256,3): 170-reg budget, 3 blk/CU.
// Inline searchsorted; pitch blocks export idx as a by-product.
// OOB-zero folded into the LN writeback.
// ============================================================
__global__ __launch_bounds__(256, 3) void fused_all_kernel(
    const short* __restrict__ xbf, const int* __restrict__ cum,
    const int* __restrict__ mel_i, const unsigned char* __restrict__ src_mask,
    const short* __restrict__ wt_base, const float* __restrict__ corr_base,
    int* __restrict__ idx_out, PArgs pa, PArgs ea, PArgs da) {
  __shared__ short a_lds[ARB * ALD];         // 35.9KB; input tile then L1 output
  __shared__ int   s_idx[ARB];
  __shared__ float s_sc[ARB];
  __shared__ float part_s[MB][4];            // reused for projection partials
  __shared__ float part_s2[MB][4];
  __shared__ float part_sx[16][4];
  __shared__ float part_s2x[16][4];
  __shared__ float smean[MB], srstd[MB];
  __shared__ float smeanx[16], srstdx[16];

  const int tid = threadIdx.x;
  const int gid = blockIdx.x;

  int pred, loc;
  if (gid < 1024)      { pred = 0; loc = gid; }
  else if (gid < 2048) { pred = 1; loc = gid - 1024; }
  else                 { pred = 2; loc = gid - 2048; }
  const bool gather = pred < 2;
  const int tile = gather ? (loc & 31) : (loc & 7);
  const int b    = gather ? (loc >> 5) : (loc >> 3);
  const int N    = gather ? Tc : Sc;
  const int s0   = tile * MB;

  PArgs ar = pred == 0 ? pa : (pred == 1 ? ea : da);
  const short* wt1 = wt_base + (size_t)(pred * 2) * WTSZ;
  const short* wt2 = wt1 + WTSZ;
  const float* corr = corr_base + (size_t)pred * 6 * 256;   // valid for pred<2

  const int lane = tid & 63, wv = tid >> 6;       // wv 0..3
  const int l15 = lane & 15, quad = lane >> 4;
  const int co0 = wv * 64;                        // wave's co quarter

  // ---- phase A: inline searchsorted + sc preload (gather path) ----
  // pitch blocks (pred==0) cover every (b,t) exactly once: export idx
  // as a by-product for final_kernel (own value, no barrier needed).
  if (gather) {
    if (tid < ARB) {
      int t = s0 - 2 + tid;
      bool v = (t >= 0 && t < N && t < mel_i[b]);
      int i = v ? ssearch(cum + b * Sc, t) : -1;
      s_idx[tid] = i;
      s_sc[tid] = v ? ar.sc[b * Sc + i] : 0.0f;
      if (pred == 0 && tid >= 2 && tid < 2 + MB) idx_out[b * Tc + t] = i;
    }
    __syncthreads();
  }

  // ---- phase B: bf16 row staging (pure copies, 8 rows/iter) ----
  {
    int r0 = tid >> 5, c0 = (tid & 31) * 8;
    #pragma unroll
    for (int it = 0; it < 9; it++) {
      int r = it * 8 + r0;
      if (r < ARB) {
        U16 v;
        if (gather) {
          int i = s_idx[r];
          int is = i < 0 ? 0 : i;
          v = *(const U16*)(xbf + ((size_t)b * Sc + is) * Hc + c0);
          if (i < 0) { v.a = 0; v.b = 0; }
        } else {
          int t = s0 - 2 + r;
          int ts = t < 0 ? 0 : (t > N - 1 ? N - 1 : t);
          v = *(const U16*)(xbf + ((size_t)b * N + ts) * Hc + c0);
          if (t < 0 || t >= N) { v.a = 0; v.b = 0; }
        }
        *(U16*)&a_lds[r * ALD + c0] = v;
      }
    }
  }
  __syncthreads();

  // ---- K-loop 1: conv layer-1, 64 main rows + folded halo tile ----
  f32x4 acc[4][4];
  f32x4 accx[4];
  #pragma unroll
  for (int i = 0; i < 4; i++) {
    accx[i] = (f32x4){0.f, 0.f, 0.f, 0.f};
    #pragma unroll
    for (int j = 0; j < 4; j++) acc[i][j] = (f32x4){0.f, 0.f, 0.f, 0.f};
  }
  const short* wp1 = wt1 + (size_t)(co0 + l15) * KW + quad * 8;
  run_kloop<true>(wp1, a_lds, l15, quad, acc, accx);

  // ---- epilogue-1: bias (+rank-6 sc correction) + ReLU + LN stats ----
  float cbv[4], gv[4], bv2[4];
  #pragma unroll
  for (int nt = 0; nt < 4; nt++) {
    int ch = co0 + nt * 16 + l15;
    cbv[nt] = ar.cb1[ch]; gv[nt] = ar.lng1[ch]; bv2[nt] = ar.lnb1[ch];
  }
  float a1v[3][4], b1v[3][4];
  if (gather) {
    #pragma unroll
    for (int k = 0; k < 3; k++)
      #pragma unroll
      for (int nt = 0; nt < 4; nt++) {
        int ch = co0 + nt * 16 + l15;
        a1v[k][nt] = corr[k * 256 + ch];
        b1v[k][nt] = corr[(3 + k) * 256 + ch];
      }
  }
  #pragma unroll
  for (int mt = 0; mt < 4; mt++)
    #pragma unroll
    for (int r = 0; r < 4; r++) {
      int p = mt * 16 + quad * 4 + r;          // L1 row, inputs p..p+2
      float c0s = 0.f, c1s = 0.f, c2s = 0.f, w0 = 0.f, w1 = 0.f, w2 = 0.f;
      if (gather) {
        c0s = s_sc[p]; c1s = s_sc[p + 1]; c2s = s_sc[p + 2];
        w0 = s_idx[p]     >= 0 ? 1.f : 0.f;
        w1 = s_idx[p + 1] >= 0 ? 1.f : 0.f;
        w2 = s_idx[p + 2] >= 0 ? 1.f : 0.f;
      }
      float s = 0.f, s2 = 0.f;
      #pragma unroll
      for (int nt = 0; nt < 4; nt++) {
        float v = acc[mt][nt][r] + cbv[nt];
        if (gather)
          v += c0s * a1v[0][nt] + c1s * a1v[1][nt] + c2s * a1v[2][nt]
             + w0 * b1v[0][nt] + w1 * b1v[1][nt] + w2 * b1v[2][nt];
        v = fmaxf(v, 0.f);
        acc[mt][nt][r] = v;
        s += v; s2 += v * v;
      }
      #pragma unroll
      for (int d = 1; d <= 8; d <<= 1) {
        s += __shfl_xor(s, d, 64);
        s2 += __shfl_xor(s2, d, 64);
      }
      if (l15 == 0) {
        part_s[p][wv] = s; part_s2[p][wv] = s2;
      }
    }

  // ---- halo epilogue: bias (+corr) + ReLU + row stats (rows 64..79) ----
  #pragma unroll
  for (int r = 0; r < 4; r++) {
    int p = 64 + quad * 4 + r;            // L1 row index (garbage for p>=66)
    int i0 = p, i1 = p + 1, i2 = p + 2;
    if (i0 > ARB - 1) i0 = ARB - 1;
    if (i1 > ARB - 1) i1 = ARB - 1;
    if (i2 > ARB - 1) i2 = ARB - 1;
    float c0s = 0.f, c1s = 0.f, c2s = 0.f, w0 = 0.f, w1 = 0.f, w2 = 0.f;
    if (gather) {
      c0s = s_sc[i0]; c1s = s_sc[i1]; c2s = s_sc[i2];
      w0 = s_idx[i0] >= 0 ? 1.f : 0.f;
      w1 = s_idx[i1] >= 0 ? 1.f : 0.f;
      w2 = s_idx[i2] >= 0 ? 1.f : 0.f;
    }
    float s = 0.f, s2 = 0.f;
    #pragma unroll
    for (int nt = 0; nt < 4; nt++) {
      float v = accx[nt][r] + cbv[nt];
      if (gather)
        v += c0s * a1v[0][nt] + c1s * a1v[1][nt] + c2s * a1v[2][nt]
           + w0 * b1v[0][nt] + w1 * b1v[1][nt] + w2 * b1v[2][nt];
      v = fmaxf(v, 0.f);
      accx[nt][r] = v;
      s += v; s2 += v * v;
    }
    #pragma unroll
    for (int d = 1; d <= 8; d <<= 1) {
      s += __shfl_xor(s, d, 64);
      s2 += __shfl_xor(s2, d, 64);
    }
    if (l15 == 0) {
      part_sx[quad * 4 + r][wv] = s; part_s2x[quad * 4 + r][wv] = s2;
    }
  }
  __syncthreads();
  if (tid < MB) {
    float s  = part_s[tid][0] + part_s[tid][1] + part_s[tid][2] + part_s[tid][3];
    float s2 = part_s2[tid][0] + part_s2[tid][1] + part_s2[tid][2] + part_s2[tid][3];
    float m = s * (1.f / Fc);
    float var = s2 * (1.f / Fc) - m * m;
    smean[tid] = m; srstd[tid] = rsqrtf(var + EPSc);
  } else if (tid < MB + 16) {
    int i = tid - MB;
    float s  = part_sx[i][0] + part_sx[i][1] + part_sx[i][2] + part_sx[i][3];
    float s2 = part_s2x[i][0] + part_s2x[i][1] + part_s2x[i][2] + part_s2x[i][3];
    float m = s * (1.f / Fc);
    float var = s2 * (1.f / Fc) - m * m;
    smeanx[i] = m; srstdx[i] = rsqrtf(var + EPSc);
  }
  __syncthreads();

  // ---- LN apply + writeback with OOB-zero folded in (SAME padding) ----
  // main rows 0..63, halo rows 64,65; t outside [0,N) -> write 0.
  #pragma unroll
  for (int mt = 0; mt < 4; mt++)
    #pragma unroll
    for (int r = 0; r < 4; r++) {
      int p = mt * 16 + quad * 4 + r;
      int t = s0 - 1 + p;
      bool oob = (t < 0 || t >= N);
      float m = smean[p], rs = srstd[p];
      #pragma unroll
      for (int nt = 0; nt < 4; nt++) {
        float v = oob ? 0.f : (acc[mt][nt][r] - m) * rs * gv[nt] + bv2[nt];
        a_lds[p * ALD + co0 + nt * 16 + l15] = f2bf(v);
      }
    }
  #pragma unroll
  for (int r = 0; r < 4; r++) {
    int p = 64 + quad * 4 + r;
    if (p < 66) {
      int t = s0 - 1 + p;
      bool oob = (t < 0 || t >= N);
      float m = smeanx[p - 64], rs = srstdx[p - 64];
      #pragma unroll
      for (int nt = 0; nt < 4; nt++) {
        float v = oob ? 0.f : (accx[nt][r] - m) * rs * gv[nt] + bv2[nt];
        a_lds[p * ALD + co0 + nt * 16 + l15] = f2bf(v);
      }
    }
  }
  __syncthreads();

  // ---- K-loop 2: conv layer-2 (reads L1 rows 0..65 from LDS) ----
  #pragma unroll
  for (int i = 0; i < 4; i++)
    #pragma unroll
    for (int j = 0; j < 4; j++) acc[i][j] = (f32x4){0.f, 0.f, 0.f, 0.f};
  const short* wp2 = wt2 + (size_t)(co0 + l15) * KW + quad * 8;
  run_kloop<false>(wp2, a_lds, l15, quad, acc, accx);

  // ---- epilogue-2: bias + ReLU + LN stats ----
  float lwv[4];
  #pragma unroll
  for (int nt = 0; nt < 4; nt++) {
    int ch = co0 + nt * 16 + l15;
    cbv[nt] = ar.cb2[ch]; gv[nt] = ar.lng2[ch]; bv2[nt] = ar.lnb2[ch]; lwv[nt] = ar.lw[ch];
  }
  #pragma unroll
  for (int mt = 0; mt < 4; mt++)
    #pragma unroll
    for (int r = 0; r < 4; r++) {
      float s = 0.f, s2 = 0.f;
      #pragma unroll
      for (int nt = 0; nt < 4; nt++) {
        float v = fmaxf(acc[mt][nt][r] + cbv[nt], 0.f);
        acc[mt][nt][r] = v;
        s += v; s2 += v * v;
      }
      #pragma unroll
      for (int d = 1; d <= 8; d <<= 1) {
        s += __shfl_xor(s, d, 64);
        s2 += __shfl_xor(s2, d, 64);
      }
      if (l15 == 0) {
        int p = mt * 16 + quad * 4 + r;
        part_s[p][wv] = s; part_s2[p][wv] = s2;
      }
    }
  __syncthreads();
  if (tid < MB) {
    float s  = part_s[tid][0] + part_s[tid][1] + part_s[tid][2] + part_s[tid][3];
    float s2 = part_s2[tid][0] + part_s2[tid][1] + part_s2[tid][2] + part_s2[tid][3];
    float m = s * (1.f / Fc);
    float var = s2 * (1.f / Fc) - m * m;
    smean[tid] = m; srstd[tid] = rsqrtf(var + EPSc);
  }
  __syncthreads();

  // ---- LN apply + projection reduce (part_s reused as partials) ----
  #pragma unroll
  for (int mt = 0; mt < 4; mt++)
    #pragma unroll
    for (int r = 0; r < 4; r++) {
      int p = mt * 16 + quad * 4 + r;
      float m = smean[p], rs = srstd[p];
      float s = 0.f;
      #pragma unroll
      for (int nt = 0; nt < 4; nt++) {
        float v = (acc[mt][nt][r] - m) * rs * gv[nt] + bv2[nt];
        s += v * lwv[nt];
      }
      #pragma unroll
      for (int d = 1; d <= 8; d <<= 1) s += __shfl_xor(s, d, 64);
      if (l15 == 0) part_s[p][wv] = s;
    }
  __syncthreads();
  if (tid < MB) {
    int t = s0 + tid;
    if (t < N) {
      float o = part_s[tid][0] + part_s[tid][1] + part_s[tid][2] + part_s[tid][3] + ar.lb[0];
      bool masked;
      if (gather) masked = !(t < mel_i[b]);
      else        masked = (src_mask[(size_t)b * N + t] != 0);
      ar.pred[(size_t)b * N + t] = masked ? 0.f : o;
    }
  }
}

// ============================================================
// out = xe + pp*pc2_w + pc2_b + ep*ec2_w + ec2_b  (float4, 4 rows/block)
// idx from workspace (by-product of fused_all pitch blocks, L2-hot);
// also writes mel_mask.
// ============================================================
__global__ __launch_bounds__(256) void final_kernel(
    const float* __restrict__ x, const int* __restrict__ idx,
    const int* __restrict__ mel_i,
    const float* __restrict__ pp, const float* __restrict__ ep,
    const float* __restrict__ pc2_w, const float* __restrict__ pc2_b,
    const float* __restrict__ ec2_w, const float* __restrict__ ec2_b,
    float* __restrict__ out, float* __restrict__ mmask) {
  int bt = blockIdx.x * 4 + (threadIdx.x >> 6);
  int lane = threadIdx.x & 63;
  int b = bt >> 11, t = bt & (Tc - 1);
  int c4 = lane * 4;
  int i = idx[bt];
  bool val = t < mel_i[b];
  if (lane == 0) mmask[bt] = val ? 0.0f : 1.0f;
  int is = i < 0 ? 0 : i;               // -1 marks invalid rows (masked below)
  float4 xv = *(const float4*)(x + ((size_t)b * Sc + is) * Hc + c4);
  float p = pp[bt], e = ep[bt];
  float4 pw = *(const float4*)(pc2_w + c4);
  float4 pb = *(const float4*)(pc2_b + c4);
  float4 ew = *(const float4*)(ec2_w + c4);
  float4 eb = *(const float4*)(ec2_b + c4);
  float4 o;
  o.x = (val ? xv.x : 0.f) + p * pw.x + pb.x + e * ew.x + eb.x;
  o.y = (val ? xv.y : 0.f) + p * pw.y + pb.y + e * ew.y + eb.y;
  o.z = (val ? xv.z : 0.f) + p * pw.z + pb.z + e * ew.z + eb.z;
  o.w = (val ? xv.w : 0.f) + p * pw.w + pb.w + e * ew.w + eb.w;
  *(float4*)(out + (size_t)bt * Hc + c4) = o;
}

// ============================================================
extern "C" void kernel_launch(void* const* d_in, const int* in_sizes, int n_in,
                              void* d_out, int out_size, void* d_ws, size_t ws_size,
                              hipStream_t stream) {
  const float* x          = (const float*)d_in[0];
  const unsigned char* sm = (const unsigned char*)d_in[1];
  const float* src_pitch  = (const float*)d_in[3];
  const float* src_energy = (const float*)d_in[4];
  const int*   src_dur    = (const int*)d_in[5];

  const float* dur_cw = (const float*)d_in[7];
  const float* dur_cb = (const float*)d_in[8];
  const float* dur_lng= (const float*)d_in[9];
  const float* dur_lnb= (const float*)d_in[10];
  const float* dur_lw = (const float*)d_in[11];
  const float* dur_lb = (const float*)d_in[12];

  const float* pit_cw = (const float*)d_in[13];
  const float* pit_cb = (const float*)d_in[14];
  const float* pit_lng= (const float*)d_in[15];
  const float* pit_lnb= (const float*)d_in[16];
  const float* pit_lw = (const float*)d_in[17];
  const float* pit_lb = (const float*)d_in[18];

  const float* ene_cw = (const float*)d_in[19];
  const float* ene_cb = (const float*)d_in[20];
  const float* ene_lng= (const float*)d_in[21];
  const float* ene_lnb= (const float*)d_in[22];
  const float* ene_lw = (const float*)d_in[23];
  const float* ene_lb = (const float*)d_in[24];

  const float* pc1_w = (const float*)d_in[25];
  const float* pc1_b = (const float*)d_in[26];
  const float* pc2_w = (const float*)d_in[27];
  const float* pc2_b = (const float*)d_in[28];
  const float* ec1_w = (const float*)d_in[29];
  const float* ec1_b = (const float*)d_in[30];
  const float* ec2_w = (const float*)d_in[31];
  const float* ec2_b = (const float*)d_in[32];

  float* out = (float*)d_out;
  float* o_out   = out + O_OUT;
  float* o_pp    = out + O_PP;
  float* o_ep    = out + O_EP;
  float* o_logd  = out + O_LOGD;
  float* o_dur   = out + O_DUR;
  float* o_mlen  = out + O_MLEN;
  float* o_mmask = out + O_MMASK;

  char* ws = (char*)d_ws;
  int*   w_cum  = (int*)(ws + W_CUM);
  int*   w_mel  = (int*)(ws + W_MEL);
  int*   w_idx  = (int*)(ws + W_IDX);
  float* w_corr = (float*)(ws + W_CORR);
  short* w_wt   = (short*)(ws + W_WT);
  short* w_xbf  = (short*)(ws + W_XBF);

  // 1) merged prep: wprep + corr + xbf + scan
  prep_kernel<<<PREP_NB, 256, 0, stream>>>(
      pit_cw, ene_cw, dur_cw, pc1_w, pc1_b, ec1_w, ec1_b,
      x, src_dur, w_wt, w_corr, w_xbf, w_cum, w_mel, o_dur, o_mlen);

  // 2) all three predictors, one launch (2304 = 3 exact rounds of 768):
  //    blocks [0,1024) pitch, [1024,2048) energy, [2048,2304) duration
  PArgs pa = { src_pitch,
               pit_cb, pit_lng, pit_lnb,
               pit_cb + Fc, pit_lng + Fc, pit_lnb + Fc,
               pit_lw, pit_lb, o_pp };
  PArgs ea = { src_energy,
               ene_cb, ene_lng, ene_lnb,
               ene_cb + Fc, ene_lng + Fc, ene_lnb + Fc,
               ene_lw, ene_lb, o_ep };
  PArgs da = { nullptr,
               dur_cb, dur_lng, dur_lnb,
               dur_cb + Fc, dur_lng + Fc, dur_lnb + Fc,
               dur_lw, dur_lb, o_logd };
  fused_all_kernel<<<dim3(2304), 256, 0, stream>>>(
      w_xbf, w_cum, w_mel, sm, w_wt, w_corr, w_idx, pa, ea, da);

  // 3) final output (+ mel_mask), idx from workspace
  final_kernel<<<(Bc * Tc) / 4, 256, 0, stream>>>(
      x, w_idx, w_mel, o_pp, o_ep, pc2_w, pc2_b, ec2_w, ec2_b, o_out, o_mmask);
}

// Round 10
// 402.659 us; speedup vs baseline: 1.0359x; 1.0169x over previous
//
#include <hip/hip_runtime.h>
#include <cstddef>

// Problem constants (match reference)
constexpr int Bc = 32;    // batch
constexpr int Sc = 512;   // source length
constexpr int Hc = 256;   // hidden
constexpr int Fc = 256;   // filter
constexpr int Tc = 2048;  // max mel length
constexpr int Kc = 3;     // conv kernel
constexpr float EPSc = 1e-5f;

// MFMA types
typedef __attribute__((ext_vector_type(8))) short bf16x8;
typedef __attribute__((ext_vector_type(4))) float f32x4;
typedef unsigned long long ull;
struct alignas(16) U16 { ull a, b; };

// Tiling: fused L1+L2, MB=64 L2 output rows per 256-thread block.
// launch_bounds(256,3): 170-reg budget, 3 blocks/CU, LDS ~40KB x3.
// Grid 2304 = 3 exact rounds of 768 co-resident blocks.
// L1 rows p=0..63 (t=s0-1+p) PLUS halo rows 64,65 folded into the SAME
// K1 loop as a 5th row-tile (B fragments reused; no extra B stream).
// Input staged ARB=68 rows (t = s0-2 .. s0+65).
// LN stats computed INLINE in writeback/projection (float4 broadcast
// reads of the partials) — saves 2 barriers + 2 idle phases vs smean[].
constexpr int ALD = 264;     // LDS row stride (shorts): 4-dword row bank-shift -> 2-way max (free)
constexpr int MB  = 64;      // L2 output rows per block (divides T and S)
constexpr int ARB = 68;      // staged input rows

// Weight tensor: [co][k*256+ci] bf16, row stride 768
constexpr int KW = 768;
constexpr int KW16 = 16 * KW;               // 12288
constexpr size_t WTSZ = (size_t)Fc * KW;    // shorts per prepped tensor

// ---- output layout (flat f32) ----
constexpr size_t O_OUT   = 0;                                   // (B,T,H)
constexpr size_t O_PP    = O_OUT  + (size_t)Bc*Tc*Hc;           // (B,T)
constexpr size_t O_EP    = O_PP   + (size_t)Bc*Tc;              // (B,T)
constexpr size_t O_LOGD  = O_EP   + (size_t)Bc*Tc;              // (B,S)
constexpr size_t O_DUR   = O_LOGD + (size_t)Bc*Sc;              // (B,S)
constexpr size_t O_MLEN  = O_DUR  + (size_t)Bc*Sc;              // (B,)
constexpr size_t O_MMASK = O_MLEN + (size_t)Bc;                 // (B,T)

// ---- workspace layout (bytes) ----
constexpr size_t W_CUM  = 0;                 // int[B*S]
constexpr size_t W_MEL  = 0x10000;           // int[B]
constexpr size_t W_IDX  = 0x10100;           // int[B*T]
constexpr size_t W_CORR = 0x60000;           // float[2][6][256] (A1[3],B1[3] per pred)
constexpr size_t W_WT   = 0x70000;           // short[6][256][768] = 2.25MB
constexpr size_t W_XBF  = 0x2C0000;          // bf16 x: short[B][S][H] = 8MB

// prep kernel block ranges
constexpr int PREP_CR0  = 1152;   // [0,1152) wprep; [1152,1158) corr
constexpr int PREP_XB0  = 1158;   // [1158,3206) xbf: 2048 blocks
constexpr int PREP_SC0  = 3206;   // [3206,3238) scan: 32 batches
constexpr int PREP_NB   = 3238;

// per-predictor argument bundle (passed by value)
struct PArgs {
  const float *sc;                       // scalar conditioning (pitch/energy), null for dur
  const float *cb1, *lng1, *lnb1;        // layer-1 bias / LN
  const float *cb2, *lng2, *lnb2;        // layer-2 bias / LN
  const float *lw, *lb;                  // projection
  float *pred;                           // output (B,N)
};

__device__ __forceinline__ short f2bf(float f) {
  union { float f; unsigned u; } a; a.f = f;
  unsigned r = a.u + 0x7FFFu + ((a.u >> 16) & 1u);   // RNE
  return (short)(r >> 16);
}

__device__ __forceinline__ ull pack4bf(float4 v) {
  return (ull)(unsigned short)f2bf(v.x) |
         ((ull)(unsigned short)f2bf(v.y) << 16) |
         ((ull)(unsigned short)f2bf(v.z) << 32) |
         ((ull)(unsigned short)f2bf(v.w) << 48);
}

// ============================================================
// prep: wprep + corr + xbf + scan merged in one launch (block ranges).
// ============================================================
__global__ __launch_bounds__(256) void prep_kernel(
    const float* __restrict__ pit_cw, const float* __restrict__ ene_cw,
    const float* __restrict__ dur_cw,
    const float* __restrict__ pc1_w, const float* __restrict__ pc1_b,
    const float* __restrict__ ec1_w, const float* __restrict__ ec1_b,
    const float* __restrict__ x, const int* __restrict__ src_dur,
    short* __restrict__ wt, float* __restrict__ corr, short* __restrict__ xb,
    int* __restrict__ cum, int* __restrict__ mel_i,
    float* __restrict__ dur_out, float* __restrict__ mlen_out) {
  __shared__ float tile[32][33];
  const int gid = blockIdx.x;
  const int tid = threadIdx.x;

  if (gid < PREP_CR0) {
    // ---- wprep: w[k][ci][co] f32 -> w_t[co][k*256+ci] bf16 ----
    int z = gid / 192, rem = gid % 192;           // z = pred*2 + layer
    int bx = rem % 24, by = rem / 24;
    const float* base = (z >> 1) == 0 ? pit_cw : (z >> 1) == 1 ? ene_cw : dur_cw;
    const float* w = base + (size_t)(z & 1) * Kc * Fc * Fc;   // [768][256]
    short* out = wt + (size_t)z * WTSZ;                        // [256][768]
    int kci0 = bx * 32, co0 = by * 32;
    int j = tid & 31, i0 = tid >> 5;
    #pragma unroll
    for (int p = 0; p < 4; p++) {
      int i = i0 + p * 8;
      tile[i][j] = w[(size_t)(kci0 + i) * Fc + co0 + j];
    }
    __syncthreads();
    #pragma unroll
    for (int p = 0; p < 4; p++) {
      int i = i0 + p * 8;
      out[(size_t)(co0 + i) * KW + kci0 + j] = f2bf(tile[j][i]);
    }
  } else if (gid < PREP_XB0) {
    // ---- corr: A1[k][co] = sum_ci w[k][ci][co]*scw[ci]; B1 with scb ----
    int id = gid - PREP_CR0;
    int p = id / 3, k = id % 3;
    int co = tid;
    const float* w   = p == 0 ? pit_cw : ene_cw;
    const float* scw = p == 0 ? pc1_w : ec1_w;
    const float* scb = p == 0 ? pc1_b : ec1_b;
    float a = 0.f, bsum = 0.f;
    for (int ci = 0; ci < 256; ci++) {
      float wv = w[(size_t)((k << 8) + ci) * 256 + co];
      a += wv * scw[ci];
      bsum += wv * scb[ci];
    }
    float* o = corr + (size_t)p * 6 * 256;
    o[k * 256 + co] = a;
    o[(3 + k) * 256 + co] = bsum;
  } else if (gid < PREP_SC0) {
    // ---- xbf: x -> bf16, 8 floats/thread ----
    size_t g = (size_t)(gid - PREP_XB0) * 256 + tid;
    float4 v0 = *(const float4*)(x + g * 8);
    float4 v1 = *(const float4*)(x + g * 8 + 4);
    U16 o; o.a = pack4bf(v0); o.b = pack4bf(v1);
    *(U16*)(xb + g * 8) = o;
  } else {
    // ---- scan: per-batch inclusive duration scan (first 64 threads) ----
    if (tid < 64) {
      int b = gid - PREP_SC0;
      int lane = tid;
      const int per = Sc / 64;                // 8
      int base = b * Sc + lane * per;
      int v[per];
      int s = 0;
      #pragma unroll
      for (int i = 0; i < per; i++) { v[i] = src_dur[base + i]; s += v[i]; }
      int pre = s;
      #pragma unroll
      for (int d = 1; d < 64; d <<= 1) {
        int o = __shfl_up(pre, d, 64);
        if (lane >= d) pre += o;
      }
      int run = pre - s;
      #pragma unroll
      for (int i = 0; i < per; i++) {
        run += v[i];
        cum[base + i] = run;
        dur_out[base + i] = (float)v[i];
      }
      if (lane == 63) { mel_i[b] = run; mlen_out[b] = (float)run; }
    }
  }
}

// ============================================================
// searchsorted(cum, t, 'right') -> idx ; mel_mask output
// ============================================================
__global__ void idx_kernel(const int* __restrict__ cum, const int* __restrict__ mel_i,
                           int* __restrict__ idx, float* __restrict__ mmask) {
  int gid = blockIdx.x * blockDim.x + threadIdx.x;   // B*T threads
  int b = gid / Tc, t = gid % Tc;
  const int* c = cum + b * Sc;
  int lo = 0, hi = Sc;
  while (lo < hi) {
    int mid = (lo + hi) >> 1;
    if (c[mid] <= t) lo = mid + 1; else hi = mid;
  }
  int i = lo > (Sc - 1) ? (Sc - 1) : lo;
  idx[gid] = i;
  mmask[gid] = (t < mel_i[b]) ? 0.0f : 1.0f;
}

// ============================================================
// Main K-loop: 768-deep (3 conv taps x 256 ci), 3-stage B prefetch.
// HALO=true additionally accumulates one 16-row halo tile (rows 64..79,
// clamped reads; only 64/65 kept) reusing the SAME B fragments.
// ============================================================
template <bool HALO>
__device__ __forceinline__ void run_kloop(const short* __restrict__ wp,
                                          const short* __restrict__ a_lds,
                                          int l15, int quad,
                                          f32x4 (&acc)[4][4], f32x4 (&accx)[4]) {
  bf16x8 vbuf[3][4];
  #pragma unroll
  for (int nt = 0; nt < 4; nt++) {
    vbuf[0][nt] = *(const bf16x8*)(wp + nt * KW16);
    vbuf[1][nt] = *(const bf16x8*)(wp + nt * KW16 + 32);
  }
  #pragma unroll 1
  for (int kb = 0; kb < 24; kb += 3) {
    #pragma unroll
    for (int sub = 0; sub < 3; sub++) {
      int kbi = kb + sub;
      int kld = kbi + 2; if (kld > 23) kld = 23;
      #pragma unroll
      for (int nt = 0; nt < 4; nt++)
        vbuf[(sub + 2) % 3][nt] = *(const bf16x8*)(wp + nt * KW16 + kld * 32);
      const int kk = kbi >> 3, ci0 = (kbi & 7) * 32;
      bf16x8 av[4];
      #pragma unroll
      for (int mt = 0; mt < 4; mt++)
        av[mt] = *(const bf16x8*)&a_lds[(mt * 16 + l15 + kk) * ALD + ci0 + quad * 8];
      bf16x8 ax;
      if (HALO) {
        int rx = 64 + l15 + kk; if (rx > ARB - 1) rx = ARB - 1;  // clamp, discarded
        ax = *(const bf16x8*)&a_lds[rx * ALD + ci0 + quad * 8];
      }
      #pragma unroll
      for (int mt = 0; mt < 4; mt++)
        #pragma unroll
        for (int nt = 0; nt < 4; nt++)
          acc[mt][nt] = __builtin_amdgcn_mfma_f32_16x16x32_bf16(av[mt], vbuf[sub % 3][nt], acc[mt][nt], 0, 0, 0);
      if (HALO) {
        #pragma unroll
        for (int nt = 0; nt < 4; nt++)
          accx[nt] = __builtin_amdgcn_mfma_f32_16x16x32_bf16(ax, vbuf[sub % 3][nt], accx[nt], 0, 0, 0);
      }
    }
  }
}

// ============================================================
// Merged fused variance-predictor: all 3 predictors in one launch.
// blocks [0,1024) pitch, [1024,2048) energy, [2048,2304) duration.
// 256 thr (4 waves), MB=64 rows/block, (256,3): 170-reg budget, 3 blk/CU.
// idx from idx_kernel; LN stats inlined (2 fewer barriers); OOB-zero
// folded into the writeback (phase+barrier removed).
// ============================================================
__global__ __launch_bounds__(256, 3) void fused_all_kernel(
    const short* __restrict__ xbf, const int* __restrict__ idx,
    const int* __restrict__ mel_i, const unsigned char* __restrict__ src_mask,
    const short* __restrict__ wt_base, const float* __restrict__ corr_base,
    PArgs pa, PArgs ea, PArgs da) {
  __shared__ short a_lds[ARB * ALD];         // 35.9KB; input tile then L1 output
  __shared__ int   s_idx[ARB];
  __shared__ float s_sc[ARB];
  __shared__ alignas(16) float part_s[MB][4];
  __shared__ alignas(16) float part_s2[MB][4];
  __shared__ alignas(16) float part_p[MB][4];   // projection partials
  __shared__ alignas(16) float part_sx[16][4];
  __shared__ alignas(16) float part_s2x[16][4];

  const int tid = threadIdx.x;
  const int gid = blockIdx.x;

  int pred, loc;
  if (gid < 1024)      { pred = 0; loc = gid; }
  else if (gid < 2048) { pred = 1; loc = gid - 1024; }
  else                 { pred = 2; loc = gid - 2048; }
  const bool gather = pred < 2;
  const int tile = gather ? (loc & 31) : (loc & 7);
  const int b    = gather ? (loc >> 5) : (loc >> 3);
  const int N    = gather ? Tc : Sc;
  const int s0   = tile * MB;

  PArgs ar = pred == 0 ? pa : (pred == 1 ? ea : da);
  const short* wt1 = wt_base + (size_t)(pred * 2) * WTSZ;
  const short* wt2 = wt1 + WTSZ;
  const float* corr = corr_base + (size_t)pred * 6 * 256;   // valid for pred<2

  const int lane = tid & 63, wv = tid >> 6;       // wv 0..3
  const int l15 = lane & 15, quad = lane >> 4;
  const int co0 = wv * 64;                        // wave's co quarter

  // ---- phase A: idx/sc preload (gather path) ----
  if (gather) {
    if (tid < ARB) {
      int t = s0 - 2 + tid;
      bool v = (t >= 0 && t < N && t < mel_i[b]);
      int i = v ? idx[b * Tc + t] : -1;
      s_idx[tid] = i;
      s_sc[tid] = v ? ar.sc[b * Sc + i] : 0.0f;
    }
    __syncthreads();
  }

  // ---- phase B: bf16 row staging (pure copies, 8 rows/iter) ----
  {
    int r0 = tid >> 5, c0 = (tid & 31) * 8;
    #pragma unroll
    for (int it = 0; it < 9; it++) {
      int r = it * 8 + r0;
      if (r < ARB) {
        U16 v;
        if (gather) {
          int i = s_idx[r];
          int is = i < 0 ? 0 : i;
          v = *(const U16*)(xbf + ((size_t)b * Sc + is) * Hc + c0);
          if (i < 0) { v.a = 0; v.b = 0; }
        } else {
          int t = s0 - 2 + r;
          int ts = t < 0 ? 0 : (t > N - 1 ? N - 1 : t);
          v = *(const U16*)(xbf + ((size_t)b * N + ts) * Hc + c0);
          if (t < 0 || t >= N) { v.a = 0; v.b = 0; }
        }
        *(U16*)&a_lds[r * ALD + c0] = v;
      }
    }
  }
  __syncthreads();

  // ---- K-loop 1: conv layer-1, 64 main rows + folded halo tile ----
  f32x4 acc[4][4];
  f32x4 accx[4];
  #pragma unroll
  for (int i = 0; i < 4; i++) {
    accx[i] = (f32x4){0.f, 0.f, 0.f, 0.f};
    #pragma unroll
    for (int j = 0; j < 4; j++) acc[i][j] = (f32x4){0.f, 0.f, 0.f, 0.f};
  }
  const short* wp1 = wt1 + (size_t)(co0 + l15) * KW + quad * 8;
  run_kloop<true>(wp1, a_lds, l15, quad, acc, accx);

  // ---- epilogue-1: bias (+rank-6 sc correction) + ReLU + LN stats ----
  float cbv[4], gv[4], bv2[4];
  #pragma unroll
  for (int nt = 0; nt < 4; nt++) {
    int ch = co0 + nt * 16 + l15;
    cbv[nt] = ar.cb1[ch]; gv[nt] = ar.lng1[ch]; bv2[nt] = ar.lnb1[ch];
  }
  float a1v[3][4], b1v[3][4];
  if (gather) {
    #pragma unroll
    for (int k = 0; k < 3; k++)
      #pragma unroll
      for (int nt = 0; nt < 4; nt++) {
        int ch = co0 + nt * 16 + l15;
        a1v[k][nt] = corr[k * 256 + ch];
        b1v[k][nt] = corr[(3 + k) * 256 + ch];
      }
  }
  #pragma unroll
  for (int mt = 0; mt < 4; mt++)
    #pragma unroll
    for (int r = 0; r < 4; r++) {
      int p = mt * 16 + quad * 4 + r;          // L1 row, inputs p..p+2
      float c0s = 0.f, c1s = 0.f, c2s = 0.f, w0 = 0.f, w1 = 0.f, w2 = 0.f;
      if (gather) {
        c0s = s_sc[p]; c1s = s_sc[p + 1]; c2s = s_sc[p + 2];
        w0 = s_idx[p]     >= 0 ? 1.f : 0.f;
        w1 = s_idx[p + 1] >= 0 ? 1.f : 0.f;
        w2 = s_idx[p + 2] >= 0 ? 1.f : 0.f;
      }
      float s = 0.f, s2 = 0.f;
      #pragma unroll
      for (int nt = 0; nt < 4; nt++) {
        float v = acc[mt][nt][r] + cbv[nt];
        if (gather)
          v += c0s * a1v[0][nt] + c1s * a1v[1][nt] + c2s * a1v[2][nt]
             + w0 * b1v[0][nt] + w1 * b1v[1][nt] + w2 * b1v[2][nt];
        v = fmaxf(v, 0.f);
        acc[mt][nt][r] = v;
        s += v; s2 += v * v;
      }
      #pragma unroll
      for (int d = 1; d <= 8; d <<= 1) {
        s += __shfl_xor(s, d, 64);
        s2 += __shfl_xor(s2, d, 64);
      }
      if (l15 == 0) {
        part_s[p][wv] = s; part_s2[p][wv] = s2;
      }
    }

  // ---- halo epilogue: bias (+corr) + ReLU + row stats (rows 64..79) ----
  #pragma unroll
  for (int r = 0; r < 4; r++) {
    int p = 64 + quad * 4 + r;            // L1 row index (garbage for p>=66)
    int i0 = p, i1 = p + 1, i2 = p + 2;
    if (i0 > ARB - 1) i0 = ARB - 1;
    if (i1 > ARB - 1) i1 = ARB - 1;
    if (i2 > ARB - 1) i2 = ARB - 1;
    float c0s = 0.f, c1s = 0.f, c2s = 0.f, w0 = 0.f, w1 = 0.f, w2 = 0.f;
    if (gather) {
      c0s = s_sc[i0]; c1s = s_sc[i1]; c2s = s_sc[i2];
      w0 = s_idx[i0] >= 0 ? 1.f : 0.f;
      w1 = s_idx[i1] >= 0 ? 1.f : 0.f;
      w2 = s_idx[i2] >= 0 ? 1.f : 0.f;
    }
    float s = 0.f, s2 = 0.f;
    #pragma unroll
    for (int nt = 0; nt < 4; nt++) {
      float v = accx[nt][r] + cbv[nt];
      if (gather)
        v += c0s * a1v[0][nt] + c1s * a1v[1][nt] + c2s * a1v[2][nt]
           + w0 * b1v[0][nt] + w1 * b1v[1][nt] + w2 * b1v[2][nt];
      v = fmaxf(v, 0.f);
      accx[nt][r] = v;
      s += v; s2 += v * v;
    }
    #pragma unroll
    for (int d = 1; d <= 8; d <<= 1) {
      s += __shfl_xor(s, d, 64);
      s2 += __shfl_xor(s2, d, 64);
    }
    if (l15 == 0) {
      part_sx[quad * 4 + r][wv] = s; part_s2x[quad * 4 + r][wv] = s2;
    }
  }
  __syncthreads();   // all stats in LDS; all a_lds input reads complete

  // ---- LN apply + writeback, stats INLINE, OOB->0 folded in ----
  #pragma unroll
  for (int mt = 0; mt < 4; mt++)
    #pragma unroll
    for (int r = 0; r < 4; r++) {
      int p = mt * 16 + quad * 4 + r;
      int t = s0 - 1 + p;
      bool oob = (t < 0 || t >= N);
      float4 ps  = *(const float4*)part_s[p];     // broadcast read
      float4 ps2 = *(const float4*)part_s2[p];
      float m = (ps.x + ps.y + ps.z + ps.w) * (1.f / Fc);
      float var = (ps2.x + ps2.y + ps2.z + ps2.w) * (1.f / Fc) - m * m;
      float rs = rsqrtf(var + EPSc);
      #pragma unroll
      for (int nt = 0; nt < 4; nt++) {
        float v = oob ? 0.f : (acc[mt][nt][r] - m) * rs * gv[nt] + bv2[nt];
        a_lds[p * ALD + co0 + nt * 16 + l15] = f2bf(v);
      }
    }
  #pragma unroll
  for (int r = 0; r < 4; r++) {
    int p = 64 + quad * 4 + r;
    if (p < 66) {
      int t = s0 - 1 + p;
      bool oob = (t < 0 || t >= N);
      float4 ps  = *(const float4*)part_sx[p - 64];
      float4 ps2 = *(const float4*)part_s2x[p - 64];
      float m = (ps.x + ps.y + ps.z + ps.w) * (1.f / Fc);
      float var = (ps2.x + ps2.y + ps2.z + ps2.w) * (1.f / Fc) - m * m;
      float rs = rsqrtf(var + EPSc);
      #pragma unroll
      for (int nt = 0; nt < 4; nt++) {
        float v = oob ? 0.f : (accx[nt][r] - m) * rs * gv[nt] + bv2[nt];
        a_lds[p * ALD + co0 + nt * 16 + l15] = f2bf(v);
      }
    }
  }
  __syncthreads();

  // ---- K-loop 2: conv layer-2 (reads L1 rows 0..65 from LDS) ----
  #pragma unroll
  for (int i = 0; i < 4; i++)
    #pragma unroll
    for (int j = 0; j < 4; j++) acc[i][j] = (f32x4){0.f, 0.f, 0.f, 0.f};
  const short* wp2 = wt2 + (size_t)(co0 + l15) * KW + quad * 8;
  run_kloop<false>(wp2, a_lds, l15, quad, acc, accx);

  // ---- epilogue-2: bias + ReLU + LN stats ----
  float lwv[4];
  #pragma unroll
  for (int nt = 0; nt < 4; nt++) {
    int ch = co0 + nt * 16 + l15;
    cbv[nt] = ar.cb2[ch]; gv[nt] = ar.lng2[ch]; bv2[nt] = ar.lnb2[ch]; lwv[nt] = ar.lw[ch];
  }
  #pragma unroll
  for (int mt = 0; mt < 4; mt++)
    #pragma unroll
    for (int r = 0; r < 4; r++) {
      float s = 0.f, s2 = 0.f;
      #pragma unroll
      for (int nt = 0; nt < 4; nt++) {
        float v = fmaxf(acc[mt][nt][r] + cbv[nt], 0.f);
        acc[mt][nt][r] = v;
        s += v; s2 += v * v;
      }
      #pragma unroll
      for (int d = 1; d <= 8; d <<= 1) {
        s += __shfl_xor(s, d, 64);
        s2 += __shfl_xor(s2, d, 64);
      }
      if (l15 == 0) {
        int p = mt * 16 + quad * 4 + r;
        part_s[p][wv] = s; part_s2[p][wv] = s2;
      }
    }
  __syncthreads();

  // ---- LN apply + projection reduce, stats INLINE ----
  #pragma unroll
  for (int mt = 0; mt < 4; mt++)
    #pragma unroll
    for (int r = 0; r < 4; r++) {
      int p = mt * 16 + quad * 4 + r;
      float4 ps  = *(const float4*)part_s[p];
      float4 ps2 = *(const float4*)part_s2[p];
      float m = (ps.x + ps.y + ps.z + ps.w) * (1.f / Fc);
      float var = (ps2.x + ps2.y + ps2.z + ps2.w) * (1.f / Fc) - m * m;
      float rs = rsqrtf(var + EPSc);
      float s = 0.f;
      #pragma unroll
      for (int nt = 0; nt < 4; nt++) {
        float v = (acc[mt][nt][r] - m) * rs * gv[nt] + bv2[nt];
        s += v * lwv[nt];
      }
      #pragma unroll
      for (int d = 1; d <= 8; d <<= 1) s += __shfl_xor(s, d, 64);
      if (l15 == 0) part_p[p][wv] = s;
    }
  __syncthreads();
  if (tid < MB) {
    int t = s0 + tid;
    if (t < N) {
      float o = part_p[tid][0] + part_p[tid][1] + part_p[tid][2] + part_p[tid][3] + ar.lb[0];
      bool masked;
      if (gather) masked = !(t < mel_i[b]);
      else        masked = (src_mask[(size_t)b * N + t] != 0);
      ar.pred[(size_t)b * N + t] = masked ? 0.f : o;
    }
  }
}

// ============================================================
// out = xe + pp*pc2_w + pc2_b + ep*ec2_w + ec2_b  (float4, 4 rows/block)
// ============================================================
__global__ __launch_bounds__(256) void final_kernel(
    const float* __restrict__ x, const int* __restrict__ idx,
    const int* __restrict__ mel_i,
    const float* __restrict__ pp, const float* __restrict__ ep,
    const float* __restrict__ pc2_w, const float* __restrict__ pc2_b,
    const float* __restrict__ ec2_w, const float* __restrict__ ec2_b,
    float* __restrict__ out) {
  int bt = blockIdx.x * 4 + (threadIdx.x >> 6);
  int lane = threadIdx.x & 63;
  int b = bt >> 11, t = bt & (Tc - 1);
  int c4 = lane * 4;
  int i = idx[bt];
  bool val = t < mel_i[b];
  float4 xv = *(const float4*)(x + ((size_t)b * Sc + i) * Hc + c4);
  float p = pp[bt], e = ep[bt];
  float4 pw = *(const float4*)(pc2_w + c4);
  float4 pb = *(const float4*)(pc2_b + c4);
  float4 ew = *(const float4*)(ec2_w + c4);
  float4 eb = *(const float4*)(ec2_b + c4);
  float4 o;
  o.x = (val ? xv.x : 0.f) + p * pw.x + pb.x + e * ew.x + eb.x;
  o.y = (val ? xv.y : 0.f) + p * pw.y + pb.y + e * ew.y + eb.y;
  o.z = (val ? xv.z : 0.f) + p * pw.z + pb.z + e * ew.z + eb.z;
  o.w = (val ? xv.w : 0.f) + p * pw.w + pb.w + e * ew.w + eb.w;
  *(float4*)(out + (size_t)bt * Hc + c4) = o;
}

// ============================================================
extern "C" void kernel_launch(void* const* d_in, const int* in_sizes, int n_in,
                              void* d_out, int out_size, void* d_ws, size_t ws_size,
                              hipStream_t stream) {
  const float* x          = (const float*)d_in[0];
  const unsigned char* sm = (const unsigned char*)d_in[1];
  const float* src_pitch  = (const float*)d_in[3];
  const float* src_energy = (const float*)d_in[4];
  const int*   src_dur    = (const int*)d_in[5];

  const float* dur_cw = (const float*)d_in[7];
  const float* dur_cb = (const float*)d_in[8];
  const float* dur_lng= (const float*)d_in[9];
  const float* dur_lnb= (const float*)d_in[10];
  const float* dur_lw = (const float*)d_in[11];
  const float* dur_lb = (const float*)d_in[12];

  const float* pit_cw = (const float*)d_in[13];
  const float* pit_cb = (const float*)d_in[14];
  const float* pit_lng= (const float*)d_in[15];
  const float* pit_lnb= (const float*)d_in[16];
  const float* pit_lw = (const float*)d_in[17];
  const float* pit_lb = (const float*)d_in[18];

  const float* ene_cw = (const float*)d_in[19];
  const float* ene_cb = (const float*)d_in[20];
  const float* ene_lng= (const float*)d_in[21];
  const float* ene_lnb= (const float*)d_in[22];
  const float* ene_lw = (const float*)d_in[23];
  const float* ene_lb = (const float*)d_in[24];

  const float* pc1_w = (const float*)d_in[25];
  const float* pc1_b = (const float*)d_in[26];
  const float* pc2_w = (const float*)d_in[27];
  const float* pc2_b = (const float*)d_in[28];
  const float* ec1_w = (const float*)d_in[29];
  const float* ec1_b = (const float*)d_in[30];
  const float* ec2_w = (const float*)d_in[31];
  const float* ec2_b = (const float*)d_in[32];

  float* out = (float*)d_out;
  float* o_out   = out + O_OUT;
  float* o_pp    = out + O_PP;
  float* o_ep    = out + O_EP;
  float* o_logd  = out + O_LOGD;
  float* o_dur   = out + O_DUR;
  float* o_mlen  = out + O_MLEN;
  float* o_mmask = out + O_MMASK;

  char* ws = (char*)d_ws;
  int*   w_cum  = (int*)(ws + W_CUM);
  int*   w_mel  = (int*)(ws + W_MEL);
  int*   w_idx  = (int*)(ws + W_IDX);
  float* w_corr = (float*)(ws + W_CORR);
  short* w_wt   = (short*)(ws + W_WT);
  short* w_xbf  = (short*)(ws + W_XBF);

  // 1) merged prep: wprep + corr + xbf + scan
  prep_kernel<<<PREP_NB, 256, 0, stream>>>(
      pit_cw, ene_cw, dur_cw, pc1_w, pc1_b, ec1_w, ec1_b,
      x, src_dur, w_wt, w_corr, w_xbf, w_cum, w_mel, o_dur, o_mlen);

  // 2) searchsorted + mel_mask output (once, fully parallel)
  idx_kernel<<<(Bc * Tc) / 256, 256, 0, stream>>>(w_cum, w_mel, w_idx, o_mmask);

  // 3) all three predictors, one launch (2304 = 3 exact rounds of 768):
  //    blocks [0,1024) pitch, [1024,2048) energy, [2048,2304) duration
  PArgs pa = { src_pitch,
               pit_cb, pit_lng, pit_lnb,
               pit_cb + Fc, pit_lng + Fc, pit_lnb + Fc,
               pit_lw, pit_lb, o_pp };
  PArgs ea = { src_energy,
               ene_cb, ene_lng, ene_lnb,
               ene_cb + Fc, ene_lng + Fc, ene_lnb + Fc,
               ene_lw, ene_lb, o_ep };
  PArgs da = { nullptr,
               dur_cb, dur_lng, dur_lnb,
               dur_cb + Fc, dur_lng + Fc, dur_lnb + Fc,
               dur_lw, dur_lb, o_logd };
  fused_all_kernel<<<dim3(2304), 256, 0, stream>>>(
      w_xbf, w_idx, w_mel, sm, w_wt, w_corr, pa, ea, da);

  // 4) final output
  final_kernel<<<(Bc * Tc) / 4, 256, 0, stream>>>(
      x, w_idx, w_mel, o_pp, o_ep, pc2_w, pc2_b, ec2_w, ec2_b, o_out);
}

// Round 11
// 394.874 us; speedup vs baseline: 1.0563x; 1.0197x over previous
//
#include <hip/hip_runtime.h>
#include <cstddef>

// Problem constants (match reference)
constexpr int Bc = 32;    // batch
constexpr int Sc = 512;   // source length
constexpr int Hc = 256;   // hidden
constexpr int Fc = 256;   // filter
constexpr int Tc = 2048;  // max mel length
constexpr int Kc = 3;     // conv kernel
constexpr float EPSc = 1e-5f;

// MFMA types
typedef __attribute__((ext_vector_type(8))) short bf16x8;
typedef __attribute__((ext_vector_type(4))) float f32x4;
typedef unsigned long long ull;
struct alignas(16) U16 { ull a, b; };

// Tiling: fused L1+L2, MB=64 L2 output rows per 256-thread block.
// launch_bounds(256,3): 170-reg budget, 3 blocks/CU, LDS ~40KB x3.
// Grid 2304 = 3 exact rounds of 768 co-resident blocks.
// XCD-grouped mapping (gid&7 = XCD under round-robin dispatch):
//   XCD 0-3 pitch (8 batches each), XCD 4-7 energy, dur in tail gids.
//   Per-XCD L2 working set: 1.5MB weights + ~2MB xbf <= 4MB L2.
// L1 rows p=0..63 (t=s0-1+p) PLUS halo rows 64,65 folded into the SAME
// K1 loop as a 5th row-tile (B fragments reused; no extra B stream).
// Input staged ARB=68 rows (t = s0-2 .. s0+65).
// LN stats computed INLINE in writeback/projection (float4 broadcast).
constexpr int ALD = 264;     // LDS row stride (shorts): 4-dword row bank-shift -> 2-way max (free)
constexpr int MB  = 64;      // L2 output rows per block (divides T and S)
constexpr int ARB = 68;      // staged input rows

// Weight tensor: [co][k*256+ci] bf16, row stride 768
constexpr int KW = 768;
constexpr int KW16 = 16 * KW;               // 12288
constexpr size_t WTSZ = (size_t)Fc * KW;    // shorts per prepped tensor

// ---- output layout (flat f32) ----
constexpr size_t O_OUT   = 0;                                   // (B,T,H)
constexpr size_t O_PP    = O_OUT  + (size_t)Bc*Tc*Hc;           // (B,T)
constexpr size_t O_EP    = O_PP   + (size_t)Bc*Tc;              // (B,T)
constexpr size_t O_LOGD  = O_EP   + (size_t)Bc*Tc;              // (B,S)
constexpr size_t O_DUR   = O_LOGD + (size_t)Bc*Sc;              // (B,S)
constexpr size_t O_MLEN  = O_DUR  + (size_t)Bc*Sc;              // (B,)
constexpr size_t O_MMASK = O_MLEN + (size_t)Bc;                 // (B,T)

// ---- workspace layout (bytes) ----
constexpr size_t W_CUM  = 0;                 // int[B*S]
constexpr size_t W_MEL  = 0x10000;           // int[B]
constexpr size_t W_IDX  = 0x10100;           // int[B*T]
constexpr size_t W_CORR = 0x60000;           // float[2][6][256] (A1[3],B1[3] per pred)
constexpr size_t W_WT   = 0x70000;           // short[6][256][768] = 2.25MB
constexpr size_t W_XBF  = 0x2C0000;          // bf16 x: short[B][S][H] = 8MB

// prep kernel block ranges
constexpr int PREP_CR0  = 1152;   // [0,1152) wprep; [1152,1158) corr
constexpr int PREP_XB0  = 1158;   // [1158,3206) xbf: 2048 blocks
constexpr int PREP_SC0  = 3206;   // [3206,3238) scan+idx: 32 batches
constexpr int PREP_NB   = 3238;

// per-predictor argument bundle (passed by value)
struct PArgs {
  const float *sc;                       // scalar conditioning (pitch/energy), null for dur
  const float *cb1, *lng1, *lnb1;        // layer-1 bias / LN
  const float *cb2, *lng2, *lnb2;        // layer-2 bias / LN
  const float *lw, *lb;                  // projection
  float *pred;                           // output (B,N)
};

__device__ __forceinline__ short f2bf(float f) {
  union { float f; unsigned u; } a; a.f = f;
  unsigned r = a.u + 0x7FFFu + ((a.u >> 16) & 1u);   // RNE
  return (short)(r >> 16);
}

__device__ __forceinline__ ull pack4bf(float4 v) {
  return (ull)(unsigned short)f2bf(v.x) |
         ((ull)(unsigned short)f2bf(v.y) << 16) |
         ((ull)(unsigned short)f2bf(v.z) << 32) |
         ((ull)(unsigned short)f2bf(v.w) << 48);
}

// ============================================================
// prep: wprep + corr + xbf + (scan + searchsorted + mmask) merged.
// ============================================================
__global__ __launch_bounds__(256) void prep_kernel(
    const float* __restrict__ pit_cw, const float* __restrict__ ene_cw,
    const float* __restrict__ dur_cw,
    const float* __restrict__ pc1_w, const float* __restrict__ pc1_b,
    const float* __restrict__ ec1_w, const float* __restrict__ ec1_b,
    const float* __restrict__ x, const int* __restrict__ src_dur,
    short* __restrict__ wt, float* __restrict__ corr, short* __restrict__ xb,
    int* __restrict__ cum, int* __restrict__ mel_i, int* __restrict__ idx,
    float* __restrict__ mmask,
    float* __restrict__ dur_out, float* __restrict__ mlen_out) {
  __shared__ float tile[32][33];
  __shared__ int scum[Sc];          // scan branch: LDS-resident cum row
  __shared__ int smel;
  const int gid = blockIdx.x;
  const int tid = threadIdx.x;

  if (gid < PREP_CR0) {
    // ---- wprep: w[k][ci][co] f32 -> w_t[co][k*256+ci] bf16 ----
    int z = gid / 192, rem = gid % 192;           // z = pred*2 + layer
    int bx = rem % 24, by = rem / 24;
    const float* base = (z >> 1) == 0 ? pit_cw : (z >> 1) == 1 ? ene_cw : dur_cw;
    const float* w = base + (size_t)(z & 1) * Kc * Fc * Fc;   // [768][256]
    short* out = wt + (size_t)z * WTSZ;                        // [256][768]
    int kci0 = bx * 32, co0 = by * 32;
    int j = tid & 31, i0 = tid >> 5;
    #pragma unroll
    for (int p = 0; p < 4; p++) {
      int i = i0 + p * 8;
      tile[i][j] = w[(size_t)(kci0 + i) * Fc + co0 + j];
    }
    __syncthreads();
    #pragma unroll
    for (int p = 0; p < 4; p++) {
      int i = i0 + p * 8;
      out[(size_t)(co0 + i) * KW + kci0 + j] = f2bf(tile[j][i]);
    }
  } else if (gid < PREP_XB0) {
    // ---- corr: A1[k][co] = sum_ci w[k][ci][co]*scw[ci]; B1 with scb ----
    int id = gid - PREP_CR0;
    int p = id / 3, k = id % 3;
    int co = tid;
    const float* w   = p == 0 ? pit_cw : ene_cw;
    const float* scw = p == 0 ? pc1_w : ec1_w;
    const float* scb = p == 0 ? pc1_b : ec1_b;
    float a = 0.f, bsum = 0.f;
    for (int ci = 0; ci < 256; ci++) {
      float wv = w[(size_t)((k << 8) + ci) * 256 + co];
      a += wv * scw[ci];
      bsum += wv * scb[ci];
    }
    float* o = corr + (size_t)p * 6 * 256;
    o[k * 256 + co] = a;
    o[(3 + k) * 256 + co] = bsum;
  } else if (gid < PREP_SC0) {
    // ---- xbf: x -> bf16, 8 floats/thread ----
    size_t g = (size_t)(gid - PREP_XB0) * 256 + tid;
    float4 v0 = *(const float4*)(x + g * 8);
    float4 v1 = *(const float4*)(x + g * 8 + 4);
    U16 o; o.a = pack4bf(v0); o.b = pack4bf(v1);
    *(U16*)(xb + g * 8) = o;
  } else {
    // ---- scan + searchsorted + mmask for one batch ----
    int b = gid - PREP_SC0;
    if (tid < 64) {
      int lane = tid;
      const int per = Sc / 64;                // 8
      int base = b * Sc + lane * per;
      int v[per];
      int s = 0;
      #pragma unroll
      for (int i = 0; i < per; i++) { v[i] = src_dur[base + i]; s += v[i]; }
      int pre = s;
      #pragma unroll
      for (int d = 1; d < 64; d <<= 1) {
        int o = __shfl_up(pre, d, 64);
        if (lane >= d) pre += o;
      }
      int run = pre - s;
      #pragma unroll
      for (int i = 0; i < per; i++) {
        run += v[i];
        cum[base + i] = run;
        scum[lane * per + i] = run;
        dur_out[base + i] = (float)v[i];
      }
      if (lane == 63) {
        mel_i[b] = run; mlen_out[b] = (float)run; smel = run;
      }
    }
    __syncthreads();
    int mel = smel;
    #pragma unroll
    for (int j = 0; j < Tc / 256; j++) {      // 8 searches per thread
      int t = j * 256 + tid;
      int lo = 0, hi = Sc;
      while (lo < hi) {
        int mid = (lo + hi) >> 1;
        if (scum[mid] <= t) lo = mid + 1; else hi = mid;
      }
      int i = lo > (Sc - 1) ? (Sc - 1) : lo;
      idx[b * Tc + t] = i;
      mmask[b * Tc + t] = (t < mel) ? 0.0f : 1.0f;
    }
  }
}

// ============================================================
// Main K-loop: 768-deep (3 conv taps x 256 ci), 3-stage B prefetch.
// HALO=true additionally accumulates one 16-row halo tile (rows 64..79,
// clamped reads; only 64/65 kept) reusing the SAME B fragments.
// ============================================================
template <bool HALO>
__device__ __forceinline__ void run_kloop(const short* __restrict__ wp,
                                          const short* __restrict__ a_lds,
                                          int l15, int quad,
                                          f32x4 (&acc)[4][4], f32x4 (&accx)[4]) {
  bf16x8 vbuf[3][4];
  #pragma unroll
  for (int nt = 0; nt < 4; nt++) {
    vbuf[0][nt] = *(const bf16x8*)(wp + nt * KW16);
    vbuf[1][nt] = *(const bf16x8*)(wp + nt * KW16 + 32);
  }
  #pragma unroll 1
  for (int kb = 0; kb < 24; kb += 3) {
    #pragma unroll
    for (int sub = 0; sub < 3; sub++) {
      int kbi = kb + sub;
      int kld = kbi + 2; if (kld > 23) kld = 23;
      #pragma unroll
      for (int nt = 0; nt < 4; nt++)
        vbuf[(sub + 2) % 3][nt] = *(const bf16x8*)(wp + nt * KW16 + kld * 32);
      const int kk = kbi >> 3, ci0 = (kbi & 7) * 32;
      bf16x8 av[4];
      #pragma unroll
      for (int mt = 0; mt < 4; mt++)
        av[mt] = *(const bf16x8*)&a_lds[(mt * 16 + l15 + kk) * ALD + ci0 + quad * 8];
      bf16x8 ax;
      if (HALO) {
        int rx = 64 + l15 + kk; if (rx > ARB - 1) rx = ARB - 1;  // clamp, discarded
        ax = *(const bf16x8*)&a_lds[rx * ALD + ci0 + quad * 8];
      }
      #pragma unroll
      for (int mt = 0; mt < 4; mt++)
        #pragma unroll
        for (int nt = 0; nt < 4; nt++)
          acc[mt][nt] = __builtin_amdgcn_mfma_f32_16x16x32_bf16(av[mt], vbuf[sub % 3][nt], acc[mt][nt], 0, 0, 0);
      if (HALO) {
        #pragma unroll
        for (int nt = 0; nt < 4; nt++)
          accx[nt] = __builtin_amdgcn_mfma_f32_16x16x32_bf16(ax, vbuf[sub % 3][nt], accx[nt], 0, 0, 0);
      }
    }
  }
}

// ============================================================
// Merged fused variance-predictor: all 3 predictors in one launch.
// XCD-grouped mapping (gid&7 = XCD): XCD 0-3 pitch, 4-7 energy,
// dur in the tail gids (2048..2303). Keeps each XCD's L2 working set
// (weights + its 8 batches of xbf) under 4MB -> B-stream L2-resident.
// 256 thr (4 waves), MB=64 rows/block, (256,3): 170-reg budget, 3 blk/CU.
// ============================================================
__global__ __launch_bounds__(256, 3) void fused_all_kernel(
    const short* __restrict__ xbf, const int* __restrict__ idx,
    const int* __restrict__ mel_i, const unsigned char* __restrict__ src_mask,
    const short* __restrict__ wt_base, const float* __restrict__ corr_base,
    PArgs pa, PArgs ea, PArgs da) {
  __shared__ short a_lds[ARB * ALD];         // 35.9KB; input tile then L1 output
  __shared__ int   s_idx[ARB];
  __shared__ float s_sc[ARB];
  __shared__ alignas(16) float part_s[MB][4];
  __shared__ alignas(16) float part_s2[MB][4];
  __shared__ alignas(16) float part_p[MB][4];   // projection partials
  __shared__ alignas(16) float part_sx[16][4];
  __shared__ alignas(16) float part_s2x[16][4];

  const int tid = threadIdx.x;
  const int gid = blockIdx.x;

  // XCD-grouped pred/tile decode (2304 = 8 groups x 288)
  int grp = gid & 7;          // presumed XCD (round-robin dispatch)
  int rr  = gid >> 3;         // 0..287 within group
  int pred, loc;
  if (rr < 256) { pred = (grp < 4) ? 0 : 1; loc = (grp & 3) * 256 + rr; }
  else          { pred = 2; loc = grp * 32 + (rr - 256); }
  const bool gather = pred < 2;
  const int tile = gather ? (loc & 31) : (loc & 7);
  const int b    = gather ? (loc >> 5) : (loc >> 3);
  const int N    = gather ? Tc : Sc;
  const int s0   = tile * MB;

  PArgs ar = pred == 0 ? pa : (pred == 1 ? ea : da);
  const short* wt1 = wt_base + (size_t)(pred * 2) * WTSZ;
  const short* wt2 = wt1 + WTSZ;
  const float* corr = corr_base + (size_t)pred * 6 * 256;   // valid for pred<2

  const int lane = tid & 63, wv = tid >> 6;       // wv 0..3
  const int l15 = lane & 15, quad = lane >> 4;
  const int co0 = wv * 64;                        // wave's co quarter

  // ---- phase A: idx/sc preload (gather path) ----
  if (gather) {
    if (tid < ARB) {
      int t = s0 - 2 + tid;
      bool v = (t >= 0 && t < N && t < mel_i[b]);
      int i = v ? idx[b * Tc + t] : -1;
      s_idx[tid] = i;
      s_sc[tid] = v ? ar.sc[b * Sc + i] : 0.0f;
    }
    __syncthreads();
  }

  // ---- phase B: bf16 row staging (pure copies, 8 rows/iter) ----
  {
    int r0 = tid >> 5, c0 = (tid & 31) * 8;
    #pragma unroll
    for (int it = 0; it < 9; it++) {
      int r = it * 8 + r0;
      if (r < ARB) {
        U16 v;
        if (gather) {
          int i = s_idx[r];
          int is = i < 0 ? 0 : i;
          v = *(const U16*)(xbf + ((size_t)b * Sc + is) * Hc + c0);
          if (i < 0) { v.a = 0; v.b = 0; }
        } else {
          int t = s0 - 2 + r;
          int ts = t < 0 ? 0 : (t > N - 1 ? N - 1 : t);
          v = *(const U16*)(xbf + ((size_t)b * N + ts) * Hc + c0);
          if (t < 0 || t >= N) { v.a = 0; v.b = 0; }
        }
        *(U16*)&a_lds[r * ALD + c0] = v;
      }
    }
  }
  __syncthreads();

  // ---- K-loop 1: conv layer-1, 64 main rows + folded halo tile ----
  f32x4 acc[4][4];
  f32x4 accx[4];
  #pragma unroll
  for (int i = 0; i < 4; i++) {
    accx[i] = (f32x4){0.f, 0.f, 0.f, 0.f};
    #pragma unroll
    for (int j = 0; j < 4; j++) acc[i][j] = (f32x4){0.f, 0.f, 0.f, 0.f};
  }
  const short* wp1 = wt1 + (size_t)(co0 + l15) * KW + quad * 8;
  run_kloop<true>(wp1, a_lds, l15, quad, acc, accx);

  // ---- epilogue-1: bias (+rank-6 sc correction) + ReLU + LN stats ----
  float cbv[4], gv[4], bv2[4];
  #pragma unroll
  for (int nt = 0; nt < 4; nt++) {
    int ch = co0 + nt * 16 + l15;
    cbv[nt] = ar.cb1[ch]; gv[nt] = ar.lng1[ch]; bv2[nt] = ar.lnb1[ch];
  }
  float a1v[3][4], b1v[3][4];
  if (gather) {
    #pragma unroll
    for (int k = 0; k < 3; k++)
      #pragma unroll
      for (int nt = 0; nt < 4; nt++) {
        int ch = co0 + nt * 16 + l15;
        a1v[k][nt] = corr[k * 256 + ch];
        b1v[k][nt] = corr[(3 + k) * 256 + ch];
      }
  }
  #pragma unroll
  for (int mt = 0; mt < 4; mt++)
    #pragma unroll
    for (int r = 0; r < 4; r++) {
      int p = mt * 16 + quad * 4 + r;          // L1 row, inputs p..p+2
      float c0s = 0.f, c1s = 0.f, c2s = 0.f, w0 = 0.f, w1 = 0.f, w2 = 0.f;
      if (gather) {
        c0s = s_sc[p]; c1s = s_sc[p + 1]; c2s = s_sc[p + 2];
        w0 = s_idx[p]     >= 0 ? 1.f : 0.f;
        w1 = s_idx[p + 1] >= 0 ? 1.f : 0.f;
        w2 = s_idx[p + 2] >= 0 ? 1.f : 0.f;
      }
      float s = 0.f, s2 = 0.f;
      #pragma unroll
      for (int nt = 0; nt < 4; nt++) {
        float v = acc[mt][nt][r] + cbv[nt];
        if (gather)
          v += c0s * a1v[0][nt] + c1s * a1v[1][nt] + c2s * a1v[2][nt]
             + w0 * b1v[0][nt] + w1 * b1v[1][nt] + w2 * b1v[2][nt];
        v = fmaxf(v, 0.f);
        acc[mt][nt][r] = v;
        s += v; s2 += v * v;
      }
      #pragma unroll
      for (int d = 1; d <= 8; d <<= 1) {
        s += __shfl_xor(s, d, 64);
        s2 += __shfl_xor(s2, d, 64);
      }
      if (l15 == 0) {
        part_s[p][wv] = s; part_s2[p][wv] = s2;
      }
    }

  // ---- halo epilogue: bias (+corr) + ReLU + row stats (rows 64..79) ----
  #pragma unroll
  for (int r = 0; r < 4; r++) {
    int p = 64 + quad * 4 + r;            // L1 row index (garbage for p>=66)
    int i0 = p, i1 = p + 1, i2 = p + 2;
    if (i0 > ARB - 1) i0 = ARB - 1;
    if (i1 > ARB - 1) i1 = ARB - 1;
    if (i2 > ARB - 1) i2 = ARB - 1;
    float c0s = 0.f, c1s = 0.f, c2s = 0.f, w0 = 0.f, w1 = 0.f, w2 = 0.f;
    if (gather) {
      c0s = s_sc[i0]; c1s = s_sc[i1]; c2s = s_sc[i2];
      w0 = s_idx[i0] >= 0 ? 1.f : 0.f;
      w1 = s_idx[i1] >= 0 ? 1.f : 0.f;
      w2 = s_idx[i2] >= 0 ? 1.f : 0.f;
    }
    float s = 0.f, s2 = 0.f;
    #pragma unroll
    for (int nt = 0; nt < 4; nt++) {
      float v = accx[nt][r] + cbv[nt];
      if (gather)
        v += c0s * a1v[0][nt] + c1s * a1v[1][nt] + c2s * a1v[2][nt]
           + w0 * b1v[0][nt] + w1 * b1v[1][nt] + w2 * b1v[2][nt];
      v = fmaxf(v, 0.f);
      accx[nt][r] = v;
      s += v; s2 += v * v;
    }
    #pragma unroll
    for (int d = 1; d <= 8; d <<= 1) {
      s += __shfl_xor(s, d, 64);
      s2 += __shfl_xor(s2, d, 64);
    }
    if (l15 == 0) {
      part_sx[quad * 4 + r][wv] = s; part_s2x[quad * 4 + r][wv] = s2;
    }
  }
  __syncthreads();   // all stats in LDS; all a_lds input reads complete

  // ---- LN apply + writeback, stats INLINE, OOB->0 folded in ----
  #pragma unroll
  for (int mt = 0; mt < 4; mt++)
    #pragma unroll
    for (int r = 0; r < 4; r++) {
      int p = mt * 16 + quad * 4 + r;
      int t = s0 - 1 + p;
      bool oob = (t < 0 || t >= N);
      float4 ps  = *(const float4*)part_s[p];     // broadcast read
      float4 ps2 = *(const float4*)part_s2[p];
      float m = (ps.x + ps.y + ps.z + ps.w) * (1.f / Fc);
      float var = (ps2.x + ps2.y + ps2.z + ps2.w) * (1.f / Fc) - m * m;
      float rs = rsqrtf(var + EPSc);
      #pragma unroll
      for (int nt = 0; nt < 4; nt++) {
        float v = oob ? 0.f : (acc[mt][nt][r] - m) * rs * gv[nt] + bv2[nt];
        a_lds[p * ALD + co0 + nt * 16 + l15] = f2bf(v);
      }
    }
  #pragma unroll
  for (int r = 0; r < 4; r++) {
    int p = 64 + quad * 4 + r;
    if (p < 66) {
      int t = s0 - 1 + p;
      bool oob = (t < 0 || t >= N);
      float4 ps  = *(const float4*)part_sx[p - 64];
      float4 ps2 = *(const float4*)part_s2x[p - 64];
      float m = (ps.x + ps.y + ps.z + ps.w) * (1.f / Fc);
      float var = (ps2.x + ps2.y + ps2.z + ps2.w) * (1.f / Fc) - m * m;
      float rs = rsqrtf(var + EPSc);
      #pragma unroll
      for (int nt = 0; nt < 4; nt++) {
        float v = oob ? 0.f : (accx[nt][r] - m) * rs * gv[nt] + bv2[nt];
        a_lds[p * ALD + co0 + nt * 16 + l15] = f2bf(v);
      }
    }
  }
  __syncthreads();

  // ---- K-loop 2: conv layer-2 (reads L1 rows 0..65 from LDS) ----
  #pragma unroll
  for (int i = 0; i < 4; i++)
    #pragma unroll
    for (int j = 0; j < 4; j++) acc[i][j] = (f32x4){0.f, 0.f, 0.f, 0.f};
  const short* wp2 = wt2 + (size_t)(co0 + l15) * KW + quad * 8;
  run_kloop<false>(wp2, a_lds, l15, quad, acc, accx);

  // ---- epilogue-2: bias + ReLU + LN stats ----
  float lwv[4];
  #pragma unroll
  for (int nt = 0; nt < 4; nt++) {
    int ch = co0 + nt * 16 + l15;
    cbv[nt] = ar.cb2[ch]; gv[nt] = ar.lng2[ch]; bv2[nt] = ar.lnb2[ch]; lwv[nt] = ar.lw[ch];
  }
  #pragma unroll
  for (int mt = 0; mt < 4; mt++)
    #pragma unroll
    for (int r = 0; r < 4; r++) {
      float s = 0.f, s2 = 0.f;
      #pragma unroll
      for (int nt = 0; nt < 4; nt++) {
        float v = fmaxf(acc[mt][nt][r] + cbv[nt], 0.f);
        acc[mt][nt][r] = v;
        s += v; s2 += v * v;
      }
      #pragma unroll
      for (int d = 1; d <= 8; d <<= 1) {
        s += __shfl_xor(s, d, 64);
        s2 += __shfl_xor(s2, d, 64);
      }
      if (l15 == 0) {
        int p = mt * 16 + quad * 4 + r;
        part_s[p][wv] = s; part_s2[p][wv] = s2;
      }
    }
  __syncthreads();

  // ---- LN apply + projection reduce, stats INLINE ----
  #pragma unroll
  for (int mt = 0; mt < 4; mt++)
    #pragma unroll
    for (int r = 0; r < 4; r++) {
      int p = mt * 16 + quad * 4 + r;
      float4 ps  = *(const float4*)part_s[p];
      float4 ps2 = *(const float4*)part_s2[p];
      float m = (ps.x + ps.y + ps.z + ps.w) * (1.f / Fc);
      float var = (ps2.x + ps2.y + ps2.z + ps2.w) * (1.f / Fc) - m * m;
      float rs = rsqrtf(var + EPSc);
      float s = 0.f;
      #pragma unroll
      for (int nt = 0; nt < 4; nt++) {
        float v = (acc[mt][nt][r] - m) * rs * gv[nt] + bv2[nt];
        s += v * lwv[nt];
      }
      #pragma unroll
      for (int d = 1; d <= 8; d <<= 1) s += __shfl_xor(s, d, 64);
      if (l15 == 0) part_p[p][wv] = s;
    }
  __syncthreads();
  if (tid < MB) {
    int t = s0 + tid;
    if (t < N) {
      float o = part_p[tid][0] + part_p[tid][1] + part_p[tid][2] + part_p[tid][3] + ar.lb[0];
      bool masked;
      if (gather) masked = !(t < mel_i[b]);
      else        masked = (src_mask[(size_t)b * N + t] != 0);
      ar.pred[(size_t)b * N + t] = masked ? 0.f : o;
    }
  }
}

// ============================================================
// out = xe + pp*pc2_w + pc2_b + ep*ec2_w + ec2_b  (float4, 4 rows/block)
// ============================================================
__global__ __launch_bounds__(256) void final_kernel(
    const float* __restrict__ x, const int* __restrict__ idx,
    const int* __restrict__ mel_i,
    const float* __restrict__ pp, const float* __restrict__ ep,
    const float* __restrict__ pc2_w, const float* __restrict__ pc2_b,
    const float* __restrict__ ec2_w, const float* __restrict__ ec2_b,
    float* __restrict__ out) {
  int bt = blockIdx.x * 4 + (threadIdx.x >> 6);
  int lane = threadIdx.x & 63;
  int b = bt >> 11, t = bt & (Tc - 1);
  int c4 = lane * 4;
  int i = idx[bt];
  bool val = t < mel_i[b];
  float4 xv = *(const float4*)(x + ((size_t)b * Sc + i) * Hc + c4);
  float p = pp[bt], e = ep[bt];
  float4 pw = *(const float4*)(pc2_w + c4);
  float4 pb = *(const float4*)(pc2_b + c4);
  float4 ew = *(const float4*)(ec2_w + c4);
  float4 eb = *(const float4*)(ec2_b + c4);
  float4 o;
  o.x = (val ? xv.x : 0.f) + p * pw.x + pb.x + e * ew.x + eb.x;
  o.y = (val ? xv.y : 0.f) + p * pw.y + pb.y + e * ew.y + eb.y;
  o.z = (val ? xv.z : 0.f) + p * pw.z + pb.z + e * ew.z + eb.z;
  o.w = (val ? xv.w : 0.f) + p * pw.w + pb.w + e * ew.w + eb.w;
  *(float4*)(out + (size_t)bt * Hc + c4) = o;
}

// ============================================================
extern "C" void kernel_launch(void* const* d_in, const int* in_sizes, int n_in,
                              void* d_out, int out_size, void* d_ws, size_t ws_size,
                              hipStream_t stream) {
  const float* x          = (const float*)d_in[0];
  const unsigned char* sm = (const unsigned char*)d_in[1];
  const float* src_pitch  = (const float*)d_in[3];
  const float* src_energy = (const float*)d_in[4];
  const int*   src_dur    = (const int*)d_in[5];

  const float* dur_cw = (const float*)d_in[7];
  const float* dur_cb = (const float*)d_in[8];
  const float* dur_lng= (const float*)d_in[9];
  const float* dur_lnb= (const float*)d_in[10];
  const float* dur_lw = (const float*)d_in[11];
  const float* dur_lb = (const float*)d_in[12];

  const float* pit_cw = (const float*)d_in[13];
  const float* pit_cb = (const float*)d_in[14];
  const float* pit_lng= (const float*)d_in[15];
  const float* pit_lnb= (const float*)d_in[16];
  const float* pit_lw = (const float*)d_in[17];
  const float* pit_lb = (const float*)d_in[18];

  const float* ene_cw = (const float*)d_in[19];
  const float* ene_cb = (const float*)d_in[20];
  const float* ene_lng= (const float*)d_in[21];
  const float* ene_lnb= (const float*)d_in[22];
  const float* ene_lw = (const float*)d_in[23];
  const float* ene_lb = (const float*)d_in[24];

  const float* pc1_w = (const float*)d_in[25];
  const float* pc1_b = (const float*)d_in[26];
  const float* pc2_w = (const float*)d_in[27];
  const float* pc2_b = (const float*)d_in[28];
  const float* ec1_w = (const float*)d_in[29];
  const float* ec1_b = (const float*)d_in[30];
  const float* ec2_w = (const float*)d_in[31];
  const float* ec2_b = (const float*)d_in[32];

  float* out = (float*)d_out;
  float* o_out   = out + O_OUT;
  float* o_pp    = out + O_PP;
  float* o_ep    = out + O_EP;
  float* o_logd  = out + O_LOGD;
  float* o_dur   = out + O_DUR;
  float* o_mlen  = out + O_MLEN;
  float* o_mmask = out + O_MMASK;

  char* ws = (char*)d_ws;
  int*   w_cum  = (int*)(ws + W_CUM);
  int*   w_mel  = (int*)(ws + W_MEL);
  int*   w_idx  = (int*)(ws + W_IDX);
  float* w_corr = (float*)(ws + W_CORR);
  short* w_wt   = (short*)(ws + W_WT);
  short* w_xbf  = (short*)(ws + W_XBF);

  // 1) merged prep: wprep + corr + xbf + (scan + searchsorted + mmask)
  prep_kernel<<<PREP_NB, 256, 0, stream>>>(
      pit_cw, ene_cw, dur_cw, pc1_w, pc1_b, ec1_w, ec1_b,
      x, src_dur, w_wt, w_corr, w_xbf, w_cum, w_mel, w_idx, o_mmask,
      o_dur, o_mlen);

  // 2) all three predictors, one launch (2304 = 3 exact rounds of 768),
  //    XCD-grouped block mapping inside the kernel.
  PArgs pa = { src_pitch,
               pit_cb, pit_lng, pit_lnb,
               pit_cb + Fc, pit_lng + Fc, pit_lnb + Fc,
               pit_lw, pit_lb, o_pp };
  PArgs ea = { src_energy,
               ene_cb, ene_lng, ene_lnb,
               ene_cb + Fc, ene_lng + Fc, ene_lnb + Fc,
               ene_lw, ene_lb, o_ep };
  PArgs da = { nullptr,
               dur_cb, dur_lng, dur_lnb,
               dur_cb + Fc, dur_lng + Fc, dur_lnb + Fc,
               dur_lw, dur_lb, o_logd };
  fused_all_kernel<<<dim3(2304), 256, 0, stream>>>(
      w_xbf, w_idx, w_mel, sm, w_wt, w_corr, pa, ea, da);

  // 3) final output
  final_kernel<<<(Bc * Tc) / 4, 256, 0, stream>>>(
      x, w_idx, w_mel, o_pp, o_ep, pc2_w, pc2_b, ec2_w, ec2_b, o_out);
}